// Round 1
// 395.085 us; speedup vs baseline: 1.0514x; 1.0514x over previous
//
#include <hip/hip_runtime.h>
#include <hip/hip_bf16.h>

#define NU 200000
#define NM 80000
#define NT 280000   // NU + NM
#define HD 64
#define FM 20

#define BSHIFT 10
#define NBUCK ((NT + 1023) >> 10)   // 274 buckets of 1024 nodes
#define CHUNK 2048                  // edges per bucket block (611 blocks)

typedef __attribute__((ext_vector_type(8))) short short8;
typedef __attribute__((ext_vector_type(4))) float floatx4;

__device__ __forceinline__ float bfu2f(unsigned short u) {
    union { unsigned int u; float f; } c; c.u = ((unsigned int)u) << 16; return c.f;
}

__device__ __forceinline__ unsigned short f2bf_raw(float f) {
    union { float f; unsigned int u; } c; c.f = f;
    unsigned int u = c.u + 0x7FFFu + ((c.u >> 16) & 1u);   // round-nearest-even
    return (unsigned short)(u >> 16);
}

__device__ __forceinline__ float ldf(const void* p, long i, int isbf) {
    return isbf ? bfu2f(((const unsigned short*)p)[i]) : ((const float*)p)[i];
}
__device__ __forceinline__ int ldidx(const int* p, long j, int is64) {
    return is64 ? p[2 * j] : p[j];
}

// ---------------- runtime dtype probe -> flags[0]=isbf16, flags[1]=isint64
__global__ void probe_kernel(const void* user_emb, const int* ei, int* flags) {
    int t = threadIdx.x;
    int bad = 0;
    for (int i = t; i < 128; i += 64) {
        unsigned short h = ((const unsigned short*)user_emb)[i];
        unsigned int e = (h >> 7) & 0xFF;
        if (e >= 135) bad = 1;               // |x| >= 256, or Inf/NaN -> not real bf16
    }
    unsigned long long mf = __ballot(bad != 0);
    int odd_nonzero = 0;
    if (t < 16 && ei[2 * t + 1] != 0) odd_nonzero = 1;
    unsigned long long mi = __ballot(odd_nonzero != 0);
    if (t == 0) {
        flags[0] = (mf == 0) ? 1 : 0;
        flags[1] = (mi == 0) ? 1 : 0;
    }
}

// ---------------- prep A: user rows, vectorized copy/convert (8 elems/thread)
__global__ __launch_bounds__(256) void prep_user(
    const void* __restrict__ user_emb,
    unsigned short* __restrict__ xb,
    const int* __restrict__ flags)
{
    long t = (long)blockIdx.x * 256 + threadIdx.x;        // t < NU*HD/8 = 1.6M exactly
    int isbf = flags[0];
    if (isbf) {
        ((short8*)xb)[t] = ((const short8*)user_emb)[t];
    } else {
        floatx4 a = ((const floatx4*)user_emb)[2 * t];
        floatx4 b = ((const floatx4*)user_emb)[2 * t + 1];
        short8 r;
        r[0] = (short)f2bf_raw(a[0]); r[1] = (short)f2bf_raw(a[1]);
        r[2] = (short)f2bf_raw(a[2]); r[3] = (short)f2bf_raw(a[3]);
        r[4] = (short)f2bf_raw(b[0]); r[5] = (short)f2bf_raw(b[1]);
        r[6] = (short)f2bf_raw(b[2]); r[7] = (short)f2bf_raw(b[3]);
        ((short8*)xb)[t] = r;
    }
}

// ---------------- prep B: movie rows, latency-optimized rewrite.
// One wave computes 4 movies. Lane h holds lin_W[h][0..19] in registers
// (loaded once, L1-resident). The movie_x row address is wave-uniform
// (readfirstlane) so its loads scalarize to s_load and feed v_fmac as SGPR
// operands -- no shfl chain, no LDS, no barrier. 4 split accumulators
// per movie keep FMA dependency chains at length 5.
__global__ __launch_bounds__(256) void prep_movie(
    const void* __restrict__ movie_x,
    const void* __restrict__ movie_emb,
    const void* __restrict__ lin_W,
    const void* __restrict__ lin_b,
    unsigned short* __restrict__ xb,
    const int* __restrict__ flags)
{
    int isbf = flags[0];
    int tid = threadIdx.x;
    int lane = tid & 63;
    int wave = blockIdx.x * 4 + (tid >> 6);
    int m0 = __builtin_amdgcn_readfirstlane(wave << 2);   // 4 movies per wave
    if (m0 >= NM) return;

    // per-lane weight row lin_W[lane][0..19]; dword-granular loads
    float wr[FM];
    if (isbf) {
        const unsigned int* p = (const unsigned int*)((const unsigned short*)lin_W + (long)lane * FM);
        #pragma unroll
        for (int i = 0; i < FM / 2; ++i) {
            unsigned int u = p[i];
            wr[2 * i]     = bfu2f((unsigned short)(u & 0xFFFFu));
            wr[2 * i + 1] = bfu2f((unsigned short)(u >> 16));
        }
    } else {
        const floatx4* p = (const floatx4*)((const float*)lin_W + (long)lane * FM);  // 80B rows, 16B-aligned
        #pragma unroll
        for (int i = 0; i < FM / 4; ++i) {
            floatx4 v = p[i];
            wr[4 * i] = v[0]; wr[4 * i + 1] = v[1]; wr[4 * i + 2] = v[2]; wr[4 * i + 3] = v[3];
        }
    }
    float bias = ldf(lin_b, lane, isbf);

    #pragma unroll
    for (int mm = 0; mm < 4; ++mm) {
        int m = m0 + mm;
        float a0 = bias + ldf(movie_emb, (long)m * HD + lane, isbf);  // coalesced 256B/wave
        float a1 = 0.f, a2 = 0.f, a3 = 0.f;
        if (isbf) {
            const unsigned int* mr = (const unsigned int*)((const unsigned short*)movie_x + (long)m * FM);
            #pragma unroll
            for (int kk = 0; kk < FM / 2; ++kk) {                     // uniform-address dword loads
                unsigned int u = mr[kk];
                float x0 = bfu2f((unsigned short)(u & 0xFFFFu));
                float x1 = bfu2f((unsigned short)(u >> 16));
                if (kk & 1) { a2 += x0 * wr[2 * kk]; a3 += x1 * wr[2 * kk + 1]; }
                else        { a0 += x0 * wr[2 * kk]; a1 += x1 * wr[2 * kk + 1]; }
            }
        } else {
            const float* mr = (const float*)movie_x + (long)m * FM;   // uniform address -> s_load
            #pragma unroll
            for (int k = 0; k < FM; k += 4) {
                a0 += mr[k]     * wr[k];
                a1 += mr[k + 1] * wr[k + 1];
                a2 += mr[k + 2] * wr[k + 2];
                a3 += mr[k + 3] * wr[k + 3];
            }
        }
        xb[(long)(NU + m) * HD + lane] = f2bf_raw((a0 + a1) + (a2 + a3));
    }
}

// ---------------- CSR build ----------------
__global__ __launch_bounds__(256) void hist_kernel(
    const int* __restrict__ ei, int E, int* __restrict__ cnt, const int* __restrict__ flags)
{
    long e = (long)blockIdx.x * 256 + threadIdx.x;
    if (e >= E) return;
    int d = ldidx(ei, (long)E + e, flags[1]);
    atomicAdd(&cnt[d], 1);
}

__global__ __launch_bounds__(256) void scan1_kernel(const int* __restrict__ cnt, int* __restrict__ bsum)
{
    __shared__ int s[256];
    int t = threadIdx.x;
    long i = (long)blockIdx.x * 256 + t;
    s[t] = (i < NT) ? cnt[i] : 0;
    __syncthreads();
    for (int off = 128; off > 0; off >>= 1) {
        if (t < off) s[t] += s[t + off];
        __syncthreads();
    }
    if (t == 0) bsum[blockIdx.x] = s[0];
}

__global__ __launch_bounds__(256) void scan2_kernel(int* __restrict__ bsum, int NB)
{
    __shared__ int chunk[256];
    int t = threadIdx.x;
    int per = (NB + 255) / 256;
    int begin = t * per;
    int end = begin + per; if (end > NB) end = NB; if (begin > NB) begin = NB;
    int sum = 0;
    for (int i = begin; i < end; ++i) sum += bsum[i];
    chunk[t] = sum;
    __syncthreads();
    for (int off = 1; off < 256; off <<= 1) {
        int v = chunk[t];
        if (t >= off) v += chunk[t - off];
        __syncthreads();
        chunk[t] = v;
        __syncthreads();
    }
    int run = (t == 0) ? 0 : chunk[t - 1];
    for (int i = begin; i < end; ++i) {
        int v = bsum[i];
        bsum[i] = run;
        run += v;
    }
}

__global__ __launch_bounds__(256) void scan3_kernel(
    const int* __restrict__ cnt, const int* __restrict__ bsum,
    int* __restrict__ rowptr)
{
    __shared__ int s[256];
    int t = threadIdx.x;
    long i = (long)blockIdx.x * 256 + t;
    int v = (i < NT) ? cnt[i] : 0;
    s[t] = v;
    __syncthreads();
    for (int off = 1; off < 256; off <<= 1) {
        int u = s[t];
        if (t >= off) u += s[t - off];
        __syncthreads();
        s[t] = u;
        __syncthreads();
    }
    if (i < NT) rowptr[i] = bsum[blockIdx.x] + s[t] - v;   // exclusive
}

// ---------------- bucket pass v2: group edges by dst>>10 into packed (direct write)
// per-wave histograms (low contention), parallel per-bucket wave-prefix (no serial
// scan), no stage / no binary search. packed entry: (src<<10) | (dst&1023).
__global__ __launch_bounds__(256) void bucket_kernel(
    const int* __restrict__ ei, int E,
    const int* __restrict__ rowptr,
    int* __restrict__ bfill,           // NBUCK global cursors, pre-zeroed
    int* __restrict__ packed,
    const int* __restrict__ flags)
{
    __shared__ int histw[4][NBUCK];    // per-wave histogram, then wave-exclusive prefix
    __shared__ int curw[4][NBUCK];     // per-wave running cursor (pass B)
    __shared__ int wbase[NBUCK];       // global base for this block's run in bucket b

    int tid = threadIdx.x;
    int w = tid >> 6;
    int lane = tid & 63;
    int is64 = flags[1];
    long e0 = (long)blockIdx.x * CHUNK;
    long rem = (long)E - e0;
    int n = (rem < CHUNK) ? (int)rem : CHUNK;
    if (n <= 0) return;

    for (int i = tid; i < NBUCK; i += 256) {
        histw[0][i] = 0; histw[1][i] = 0; histw[2][i] = 0; histw[3][i] = 0;
        curw[0][i] = 0;  curw[1][i] = 0;  curw[2][i] = 0;  curw[3][i] = 0;
    }
    __syncthreads();

    // pass A: per-wave histogram (wave w owns edges [w*512, min((w+1)*512, n)))
    int jbeg = w * (CHUNK / 4);
    int jend = jbeg + (CHUNK / 4); if (jend > n) jend = n;
    for (int j = jbeg + lane; j < jend; j += 64) {
        int d = ldidx(ei, (long)E + e0 + j, is64);
        atomicAdd(&histw[w][d >> BSHIFT], 1);
    }
    __syncthreads();

    // reserve global runs + wave-exclusive prefix per bucket (parallel over buckets)
    for (int b = tid; b < NBUCK; b += 256) {
        int h0 = histw[0][b], h1 = histw[1][b], h2 = histw[2][b], h3 = histw[3][b];
        int hb = h0 + h1 + h2 + h3;
        int g = (hb > 0) ? atomicAdd(&bfill[b], hb) : 0;
        wbase[b] = rowptr[b << BSHIFT] + g;
        histw[0][b] = 0;
        histw[1][b] = h0;
        histw[2][b] = h0 + h1;
        histw[3][b] = h0 + h1 + h2;
    }
    __syncthreads();

    // pass B: direct write to packed (block-exclusive runs per bucket)
    for (int j = jbeg + lane; j < jend; j += 64) {
        int s = ldidx(ei, e0 + j, is64);
        int d = ldidx(ei, (long)E + e0 + j, is64);
        int b = d >> BSHIFT;
        int pos = atomicAdd(&curw[w][b], 1);
        packed[wbase[b] + histw[w][b] + pos] = (s << BSHIFT) | (d & ((1 << BSHIFT) - 1));
    }
}

// ---------------- fine fill: one block per bucket; all scattered stores confined to one ~18KB region
__global__ __launch_bounds__(256) void finefill_kernel(
    const int* __restrict__ rowptr,
    const int* __restrict__ packed,
    int* __restrict__ srclist,
    int E)
{
    __shared__ int lfill[1 << BSHIFT];
    int b = blockIdx.x;
    int tid = threadIdx.x;
    int nbase = b << BSHIFT;
    int nend = nbase + (1 << BSHIFT); if (nend > NT) nend = NT;
    int nloc = nend - nbase;
    for (int i = tid; i < nloc; i += 256) lfill[i] = rowptr[nbase + i];
    __syncthreads();
    int beg = rowptr[nbase];
    int end = (nend < NT) ? rowptr[nend] : E;
    for (int j = beg + tid; j < end; j += 256) {
        int p = packed[j];
        int dl = p & ((1 << BSHIFT) - 1);
        int pos = atomicAdd(&lfill[dl], 1);
        srclist[pos] = p >> BSHIFT;
    }
}

// ---------------- gather: meanb[n] = mean over incoming edges of x[src]
// 4 lanes per node, 16 nodes per wave. Lane owns a fixed 16-elem (32B) segment of
// its node's row => no cross-lane reduction; 16 independent load chains per wave.
__global__ __launch_bounds__(256) void gather_mean(
    const unsigned short* __restrict__ x,
    const int* __restrict__ rowptr,
    const int* __restrict__ cnt,
    const int* __restrict__ srclist,
    unsigned short* __restrict__ meanb)
{
    int wid = (blockIdx.x * 256 + threadIdx.x) >> 6;   // wave id; NT = 17500*16 exactly
    int lane = threadIdx.x & 63;
    int g = lane >> 2;          // node group 0..15
    int sub = lane & 3;         // 16-elem segment 0..3
    int n = wid * 16 + g;
    if (n >= NT) return;
    int beg = rowptr[n];
    int deg = cnt[n];

    float acc[16];
    #pragma unroll
    for (int k = 0; k < 16; ++k) acc[k] = 0.f;

    for (int j0 = 0; j0 < deg; j0 += 4) {
        int e = j0 + sub;
        int sv = (e < deg) ? srclist[beg + e] : 0;    // 4 coalesced edge-id loads per group
        int cq = deg - j0; if (cq > 4) cq = 4;
        short8 r[4][2];
        #pragma unroll
        for (int q = 0; q < 4; ++q) {                 // 8 independent 16B loads in flight
            int s = __shfl(sv, (g << 2) | q);
            const short8* p = (const short8*)&x[(long)s * HD + sub * 16];
            r[q][0] = p[0];
            r[q][1] = p[1];
        }
        #pragma unroll
        for (int q = 0; q < 4; ++q) {
            if (q < cq) {
                #pragma unroll
                for (int k = 0; k < 8; ++k) {
                    acc[k]     += bfu2f((unsigned short)r[q][0][k]);
                    acc[k + 8] += bfu2f((unsigned short)r[q][1][k]);
                }
            }
        }
    }

    float rd = 1.0f / fmaxf((float)deg, 1.0f);
    short8 o0, o1;
    #pragma unroll
    for (int k = 0; k < 8; ++k) {
        o0[k] = (short)f2bf_raw(acc[k] * rd);
        o1[k] = (short)f2bf_raw(acc[k + 8] * rd);
    }
    short8* op = (short8*)&meanb[(long)n * HD + sub * 16];
    op[0] = o0;
    op[1] = o1;
}

// ---------------- combine: out = act( mean @ Wl.T + b + xin @ Wr.T )   [in-place: out may == xin]
template <bool RELU>
__global__ __launch_bounds__(256) void combine_kernel(
    const unsigned short* __restrict__ meanb,
    const unsigned short* __restrict__ xin,
    const void* __restrict__ Wl,
    const void* __restrict__ bias,
    const void* __restrict__ Wr,
    unsigned short* __restrict__ out,
    const int* __restrict__ flags)
{
    __shared__ short8 lWl8[HD * HD / 8];
    __shared__ short8 lWr8[HD * HD / 8];
    __shared__ short8 lmean8[HD * HD / 8];
    __shared__ short8 lx8[HD * HD / 8];
    __shared__ float lb[HD];
    unsigned short* lWl  = (unsigned short*)lWl8;
    unsigned short* lWr  = (unsigned short*)lWr8;
    unsigned short* lmean = (unsigned short*)lmean8;
    unsigned short* lx   = (unsigned short*)lx8;

    int tid = threadIdx.x;
    int isbf = flags[0];
    if (isbf) {
        const short8* wl8 = (const short8*)Wl;
        const short8* wr8 = (const short8*)Wr;
        for (int i = tid; i < HD * HD / 8; i += 256) { lWl8[i] = wl8[i]; lWr8[i] = wr8[i]; }
    } else {
        const floatx4* wlf = (const floatx4*)Wl;
        const floatx4* wrf = (const floatx4*)Wr;
        for (int i = tid; i < HD * HD / 8; i += 256) {
            floatx4 a = wlf[2 * i], b = wlf[2 * i + 1];
            short8 r;
            r[0]=(short)f2bf_raw(a[0]); r[1]=(short)f2bf_raw(a[1]); r[2]=(short)f2bf_raw(a[2]); r[3]=(short)f2bf_raw(a[3]);
            r[4]=(short)f2bf_raw(b[0]); r[5]=(short)f2bf_raw(b[1]); r[6]=(short)f2bf_raw(b[2]); r[7]=(short)f2bf_raw(b[3]);
            lWl8[i] = r;
            a = wrf[2 * i]; b = wrf[2 * i + 1];
            r[0]=(short)f2bf_raw(a[0]); r[1]=(short)f2bf_raw(a[1]); r[2]=(short)f2bf_raw(a[2]); r[3]=(short)f2bf_raw(a[3]);
            r[4]=(short)f2bf_raw(b[0]); r[5]=(short)f2bf_raw(b[1]); r[6]=(short)f2bf_raw(b[2]); r[7]=(short)f2bf_raw(b[3]);
            lWr8[i] = r;
        }
    }
    if (tid < HD) lb[tid] = ldf(bias, tid, isbf);

    int tile = blockIdx.x;                 // 64 nodes per tile; NT = 64*4375 exactly
    long base = (long)tile * HD * HD;
    const short8* mv = (const short8*)(meanb + base);
    const short8* xv = (const short8*)(xin + base);
    for (int i = tid; i < HD * HD / 8; i += 256) { lmean8[i] = mv[i]; lx8[i] = xv[i]; }
    __syncthreads();      // all reads of this tile's xin complete before any in-place write below

    int w = tid >> 6;
    int lane = tid & 63;
    int mrow = lane & 15;
    int quad = lane >> 4;

    short8 am0 = *(const short8*)&lmean[(w * 16 + mrow) * HD + quad * 8];
    short8 am1 = *(const short8*)&lmean[(w * 16 + mrow) * HD + 32 + quad * 8];
    short8 ax0 = *(const short8*)&lx[(w * 16 + mrow) * HD + quad * 8];
    short8 ax1 = *(const short8*)&lx[(w * 16 + mrow) * HD + 32 + quad * 8];

    floatx4 acc[4];
    #pragma unroll
    for (int ht = 0; ht < 4; ++ht) {
        int h = ht * 16 + mrow;
        short8 bl0 = *(const short8*)&lWl[h * HD + quad * 8];
        short8 bl1 = *(const short8*)&lWl[h * HD + 32 + quad * 8];
        short8 br0 = *(const short8*)&lWr[h * HD + quad * 8];
        short8 br1 = *(const short8*)&lWr[h * HD + 32 + quad * 8];
        floatx4 a = {0.f, 0.f, 0.f, 0.f};
        a = __builtin_amdgcn_mfma_f32_16x16x32_bf16(am0, bl0, a, 0, 0, 0);
        a = __builtin_amdgcn_mfma_f32_16x16x32_bf16(am1, bl1, a, 0, 0, 0);
        a = __builtin_amdgcn_mfma_f32_16x16x32_bf16(ax0, br0, a, 0, 0, 0);
        a = __builtin_amdgcn_mfma_f32_16x16x32_bf16(ax1, br1, a, 0, 0, 0);
        acc[ht] = a;
    }

    #pragma unroll
    for (int ht = 0; ht < 4; ++ht) {
        int h = ht * 16 + mrow;
        float bv = lb[h];
        #pragma unroll
        for (int r = 0; r < 4; ++r) {
            int node = w * 16 + quad * 4 + r;
            float v = acc[ht][r] + bv;
            if (RELU) v = fmaxf(v, 0.0f);
            out[base + node * HD + h] = f2bf_raw(v);
        }
    }
}

// ---------------- final: out[e] = dot(x2[u[e]], x2[NU + m[e]])
// 4 lanes per edge, 16 edges per wave; 16B vector loads; 2-step xor reduce.
__global__ __launch_bounds__(256) void dot_kernel(
    const unsigned short* __restrict__ x2,
    const int* __restrict__ eli,
    void* __restrict__ out,
    int EL,
    const int* __restrict__ flags)
{
    int wid = (blockIdx.x * 256 + threadIdx.x) >> 6;    // global wave id
    long base = (long)wid * 16;                          // first edge of this wave
    if (base >= EL) return;
    int lane = threadIdx.x & 63;
    int isbf = flags[0];
    int is64 = flags[1];

    // lanes 0..15 load u indices, lanes 16..31 load m indices (EL % 16 == 0)
    int idxv = 0;
    if (lane < 16)      idxv = ldidx(eli, base + lane, is64);
    else if (lane < 32) idxv = ldidx(eli, (long)EL + base + (lane - 16), is64);

    int e   = lane >> 2;          // edge slot 0..15
    int seg = lane & 3;           // 16-element segment of the 64-dim row
    int u = __shfl(idxv, e);
    int m = __shfl(idxv, 16 + e);

    const short8* up = (const short8*)(x2 + (long)u * HD + seg * 16);
    const short8* mp = (const short8*)(x2 + (long)(NU + m) * HD + seg * 16);
    short8 a0 = up[0], a1 = up[1];
    short8 b0 = mp[0], b1 = mp[1];

    float p = 0.f;
    #pragma unroll
    for (int j = 0; j < 8; ++j) {
        p += bfu2f((unsigned short)a0[j]) * bfu2f((unsigned short)b0[j]);
        p += bfu2f((unsigned short)a1[j]) * bfu2f((unsigned short)b1[j]);
    }
    p += __shfl_xor(p, 1);
    p += __shfl_xor(p, 2);

    if (seg == 0) {
        long g = base + e;
        if (isbf) ((unsigned short*)out)[g] = f2bf_raw(p);
        else      ((float*)out)[g] = p;
    }
}

extern "C" void kernel_launch(void* const* d_in, const int* in_sizes, int n_in,
                              void* d_out, int out_size, void* d_ws, size_t ws_size,
                              hipStream_t stream)
{
    const void* movie_x   = d_in[0];
    const void* user_emb  = d_in[1];
    const void* movie_emb = d_in[2];
    const void* lin_W     = d_in[3];
    const void* lin_b     = d_in[4];
    const void* W1l       = d_in[5];
    const void* b1        = d_in[6];
    const void* W1r       = d_in[7];
    const void* W2l       = d_in[8];
    const void* b2        = d_in[9];
    const void* W2r       = d_in[10];
    const int* ei  = (const int*)d_in[11];
    const int* eli = (const int*)d_in[12];
    int E  = in_sizes[11] / 2;
    int EL = in_sizes[12] / 2;

    const int NB = (NT + 255) / 256;     // 1094 scan blocks

    char* w = (char*)d_ws;
    unsigned short* xb      = (unsigned short*)w;  w += (size_t)NT * HD * 2;  // 35.84 MB
    unsigned short* meanb   = (unsigned short*)w;  w += (size_t)NT * HD * 2;  // 35.84 MB
    int*            cnt     = (int*)w;             w += (size_t)NT * 4;
    int*            rowptr  = (int*)w;             w += (size_t)NT * 4;
    int*            srclist = (int*)w;             w += (size_t)E * 4;        // 5 MB
    int*            packed  = (int*)w;             w += (size_t)E * 4;        // 5 MB
    int*            bsum    = (int*)w;             w += (size_t)NB * 4;
    int*            bfill   = (int*)w;             w += (size_t)NBUCK * 4;
    int*            flags   = (int*)w;

    const int user_blocks   = (NU * HD / 8) / 256;      // 6250 exactly
    const int movie_blocks  = NM / 16;                  // 5000: 4 waves/block x 4 movies/wave
    const int edge_blocks   = (E + 255) / 256;
    const int bucket_blocks = (E + CHUNK - 1) / CHUNK;  // 611
    const int gather_blocks = ((NT / 16) * 64 + 255) / 256;  // 4375 (16 nodes/wave)
    const int tile_blocks   = NT / 64;                  // 4375
    const int dot_blocks    = ((EL + 15) / 16 + 3) / 4; // 7813

    probe_kernel<<<1, 64, 0, stream>>>(user_emb, ei, flags);

    prep_user<<<user_blocks, 256, 0, stream>>>(user_emb, xb, flags);
    prep_movie<<<movie_blocks, 256, 0, stream>>>(movie_x, movie_emb, lin_W, lin_b, xb, flags);

    // CSR build (once; reused by both layers)
    hipMemsetAsync(cnt, 0, (size_t)NT * 4, stream);
    hipMemsetAsync(bfill, 0, (size_t)NBUCK * 4, stream);
    hist_kernel<<<edge_blocks, 256, 0, stream>>>(ei, E, cnt, flags);
    scan1_kernel<<<NB, 256, 0, stream>>>(cnt, bsum);
    scan2_kernel<<<1, 256, 0, stream>>>(bsum, NB);
    scan3_kernel<<<NB, 256, 0, stream>>>(cnt, bsum, rowptr);
    bucket_kernel<<<bucket_blocks, 256, 0, stream>>>(ei, E, rowptr, bfill, packed, flags);
    finefill_kernel<<<NBUCK, 256, 0, stream>>>(rowptr, packed, srclist, E);

    // layer 1
    gather_mean<<<gather_blocks, 256, 0, stream>>>(xb, rowptr, cnt, srclist, meanb);
    combine_kernel<true><<<tile_blocks, 256, 0, stream>>>(meanb, xb, W1l, b1, W1r, xb, flags);

    // layer 2
    gather_mean<<<gather_blocks, 256, 0, stream>>>(xb, rowptr, cnt, srclist, meanb);
    combine_kernel<false><<<tile_blocks, 256, 0, stream>>>(meanb, xb, W2l, b2, W2r, xb, flags);

    // final edge dot products
    dot_kernel<<<dot_blocks, 256, 0, stream>>>(xb, eli, d_out, EL, flags);
}

// Round 2
// 356.096 us; speedup vs baseline: 1.1665x; 1.1095x over previous
//
#include <hip/hip_runtime.h>
#include <hip/hip_bf16.h>

#define NU 200000
#define NM 80000
#define NT 280000   // NU + NM
#define HD 64
#define FM 20

#define BSHIFT 10
#define NBUCK ((NT + 1023) >> 10)   // 274 buckets of 1024 nodes
#define CHUNK 2048                  // edges per bucket block (611 blocks)
#define HCHUNK 4096                 // edges per bucket_hist block

typedef __attribute__((ext_vector_type(8))) short short8;
typedef __attribute__((ext_vector_type(4))) float floatx4;

__device__ __forceinline__ float bfu2f(unsigned short u) {
    union { unsigned int u; float f; } c; c.u = ((unsigned int)u) << 16; return c.f;
}

__device__ __forceinline__ unsigned short f2bf_raw(float f) {
    union { float f; unsigned int u; } c; c.f = f;
    unsigned int u = c.u + 0x7FFFu + ((c.u >> 16) & 1u);   // round-nearest-even
    return (unsigned short)(u >> 16);
}

__device__ __forceinline__ float ldf(const void* p, long i, int isbf) {
    return isbf ? bfu2f(((const unsigned short*)p)[i]) : ((const float*)p)[i];
}
__device__ __forceinline__ int ldidx(const int* p, long j, int is64) {
    return is64 ? p[2 * j] : p[j];
}

// ---------------- runtime dtype probe -> flags[0]=isbf16, flags[1]=isint64
__global__ void probe_kernel(const void* user_emb, const int* ei, int* flags) {
    int t = threadIdx.x;
    int bad = 0;
    for (int i = t; i < 128; i += 64) {
        unsigned short h = ((const unsigned short*)user_emb)[i];
        unsigned int e = (h >> 7) & 0xFF;
        if (e >= 135) bad = 1;               // |x| >= 256, or Inf/NaN -> not real bf16
    }
    unsigned long long mf = __ballot(bad != 0);
    int odd_nonzero = 0;
    if (t < 16 && ei[2 * t + 1] != 0) odd_nonzero = 1;
    unsigned long long mi = __ballot(odd_nonzero != 0);
    if (t == 0) {
        flags[0] = (mf == 0) ? 1 : 0;
        flags[1] = (mi == 0) ? 1 : 0;
    }
}

// ---------------- prep A: user rows, vectorized copy/convert (8 elems/thread)
__global__ __launch_bounds__(256) void prep_user(
    const void* __restrict__ user_emb,
    unsigned short* __restrict__ xb,
    const int* __restrict__ flags)
{
    long t = (long)blockIdx.x * 256 + threadIdx.x;        // t < NU*HD/8 = 1.6M exactly
    int isbf = flags[0];
    if (isbf) {
        ((short8*)xb)[t] = ((const short8*)user_emb)[t];
    } else {
        floatx4 a = ((const floatx4*)user_emb)[2 * t];
        floatx4 b = ((const floatx4*)user_emb)[2 * t + 1];
        short8 r;
        r[0] = (short)f2bf_raw(a[0]); r[1] = (short)f2bf_raw(a[1]);
        r[2] = (short)f2bf_raw(a[2]); r[3] = (short)f2bf_raw(a[3]);
        r[4] = (short)f2bf_raw(b[0]); r[5] = (short)f2bf_raw(b[1]);
        r[6] = (short)f2bf_raw(b[2]); r[7] = (short)f2bf_raw(b[3]);
        ((short8*)xb)[t] = r;
    }
}

// ---------------- prep B: movie rows, latency-optimized.
// One wave computes 4 movies. Lane h holds lin_W[h][0..19] in registers;
// movie_x row address is wave-uniform (scalarizes to s_load); no shfl chain,
// no LDS, no barrier. Split accumulators keep FMA chains short.
__global__ __launch_bounds__(256) void prep_movie(
    const void* __restrict__ movie_x,
    const void* __restrict__ movie_emb,
    const void* __restrict__ lin_W,
    const void* __restrict__ lin_b,
    unsigned short* __restrict__ xb,
    const int* __restrict__ flags)
{
    int isbf = flags[0];
    int tid = threadIdx.x;
    int lane = tid & 63;
    int wave = blockIdx.x * 4 + (tid >> 6);
    int m0 = __builtin_amdgcn_readfirstlane(wave << 2);   // 4 movies per wave
    if (m0 >= NM) return;

    // per-lane weight row lin_W[lane][0..19]; dword-granular loads
    float wr[FM];
    if (isbf) {
        const unsigned int* p = (const unsigned int*)((const unsigned short*)lin_W + (long)lane * FM);
        #pragma unroll
        for (int i = 0; i < FM / 2; ++i) {
            unsigned int u = p[i];
            wr[2 * i]     = bfu2f((unsigned short)(u & 0xFFFFu));
            wr[2 * i + 1] = bfu2f((unsigned short)(u >> 16));
        }
    } else {
        const floatx4* p = (const floatx4*)((const float*)lin_W + (long)lane * FM);  // 80B rows, 16B-aligned
        #pragma unroll
        for (int i = 0; i < FM / 4; ++i) {
            floatx4 v = p[i];
            wr[4 * i] = v[0]; wr[4 * i + 1] = v[1]; wr[4 * i + 2] = v[2]; wr[4 * i + 3] = v[3];
        }
    }
    float bias = ldf(lin_b, lane, isbf);

    #pragma unroll
    for (int mm = 0; mm < 4; ++mm) {
        int m = m0 + mm;
        float a0 = bias + ldf(movie_emb, (long)m * HD + lane, isbf);  // coalesced 256B/wave
        float a1 = 0.f, a2 = 0.f, a3 = 0.f;
        if (isbf) {
            const unsigned int* mr = (const unsigned int*)((const unsigned short*)movie_x + (long)m * FM);
            #pragma unroll
            for (int kk = 0; kk < FM / 2; ++kk) {                     // uniform-address dword loads
                unsigned int u = mr[kk];
                float x0 = bfu2f((unsigned short)(u & 0xFFFFu));
                float x1 = bfu2f((unsigned short)(u >> 16));
                if (kk & 1) { a2 += x0 * wr[2 * kk]; a3 += x1 * wr[2 * kk + 1]; }
                else        { a0 += x0 * wr[2 * kk]; a1 += x1 * wr[2 * kk + 1]; }
            }
        } else {
            const float* mr = (const float*)movie_x + (long)m * FM;   // uniform address -> s_load
            #pragma unroll
            for (int k = 0; k < FM; k += 4) {
                a0 += mr[k]     * wr[k];
                a1 += mr[k + 1] * wr[k + 1];
                a2 += mr[k + 2] * wr[k + 2];
                a3 += mr[k + 3] * wr[k + 3];
            }
        }
        xb[(long)(NU + m) * HD + lane] = f2bf_raw((a0 + a1) + (a2 + a3));
    }
}

// ---------------- bucket-level histogram: per-block LDS hist over 274 buckets,
// one global atomic per (block, nonempty bucket). Replaces the per-node global
// atomic histogram entirely.
__global__ __launch_bounds__(256) void bucket_hist(
    const int* __restrict__ ei, int E,
    int* __restrict__ bcnt,
    const int* __restrict__ flags)
{
    __shared__ int h[NBUCK];
    int tid = threadIdx.x;
    for (int i = tid; i < NBUCK; i += 256) h[i] = 0;
    __syncthreads();
    int is64 = flags[1];
    long e0 = (long)blockIdx.x * HCHUNK;
    long e1 = e0 + HCHUNK; if (e1 > E) e1 = E;
    for (long j = e0 + tid; j < e1; j += 256) {
        int d = ldidx(ei, (long)E + j, is64);
        atomicAdd(&h[d >> BSHIFT], 1);
    }
    __syncthreads();
    for (int i = tid; i < NBUCK; i += 256)
        if (h[i]) atomicAdd(&bcnt[i], h[i]);
}

// ---------------- scan 274 bucket counts -> bstart[NBUCK+1] (exclusive, bstart[NBUCK]=E)
__global__ __launch_bounds__(256) void bucket_scan(
    const int* __restrict__ bcnt, int* __restrict__ bstart, int E)
{
    __shared__ int s[256];
    int t = threadIdx.x;
    int a0 = (2 * t     < NBUCK) ? bcnt[2 * t]     : 0;
    int a1 = (2 * t + 1 < NBUCK) ? bcnt[2 * t + 1] : 0;
    s[t] = a0 + a1;
    __syncthreads();
    for (int off = 1; off < 256; off <<= 1) {
        int v = s[t];
        if (t >= off) v += s[t - off];
        __syncthreads();
        s[t] = v;
        __syncthreads();
    }
    int run = (t == 0) ? 0 : s[t - 1];
    if (2 * t     < NBUCK) bstart[2 * t]     = run;
    if (2 * t + 1 < NBUCK) bstart[2 * t + 1] = run + a0;
    if (t == 0) bstart[NBUCK] = E;
}

// ---------------- bucket pass: group edges by dst>>10 into packed (direct write)
// per-wave histograms (low contention), parallel per-bucket wave-prefix.
// packed entry: (src<<10) | (dst&1023).
__global__ __launch_bounds__(256) void bucket_kernel(
    const int* __restrict__ ei, int E,
    const int* __restrict__ bstart,
    int* __restrict__ bfill,           // NBUCK global cursors, pre-zeroed
    int* __restrict__ packed,
    const int* __restrict__ flags)
{
    __shared__ int histw[4][NBUCK];    // per-wave histogram, then wave-exclusive prefix
    __shared__ int curw[4][NBUCK];     // per-wave running cursor (pass B)
    __shared__ int wbase[NBUCK];       // global base for this block's run in bucket b

    int tid = threadIdx.x;
    int w = tid >> 6;
    int lane = tid & 63;
    int is64 = flags[1];
    long e0 = (long)blockIdx.x * CHUNK;
    long rem = (long)E - e0;
    int n = (rem < CHUNK) ? (int)rem : CHUNK;
    if (n <= 0) return;

    for (int i = tid; i < NBUCK; i += 256) {
        histw[0][i] = 0; histw[1][i] = 0; histw[2][i] = 0; histw[3][i] = 0;
        curw[0][i] = 0;  curw[1][i] = 0;  curw[2][i] = 0;  curw[3][i] = 0;
    }
    __syncthreads();

    // pass A: per-wave histogram (wave w owns edges [w*512, min((w+1)*512, n)))
    int jbeg = w * (CHUNK / 4);
    int jend = jbeg + (CHUNK / 4); if (jend > n) jend = n;
    for (int j = jbeg + lane; j < jend; j += 64) {
        int d = ldidx(ei, (long)E + e0 + j, is64);
        atomicAdd(&histw[w][d >> BSHIFT], 1);
    }
    __syncthreads();

    // reserve global runs + wave-exclusive prefix per bucket (parallel over buckets)
    for (int b = tid; b < NBUCK; b += 256) {
        int h0 = histw[0][b], h1 = histw[1][b], h2 = histw[2][b], h3 = histw[3][b];
        int hb = h0 + h1 + h2 + h3;
        int g = (hb > 0) ? atomicAdd(&bfill[b], hb) : 0;
        wbase[b] = bstart[b] + g;
        histw[0][b] = 0;
        histw[1][b] = h0;
        histw[2][b] = h0 + h1;
        histw[3][b] = h0 + h1 + h2;
    }
    __syncthreads();

    // pass B: direct write to packed (block-exclusive runs per bucket)
    for (int j = jbeg + lane; j < jend; j += 64) {
        int s = ldidx(ei, e0 + j, is64);
        int d = ldidx(ei, (long)E + e0 + j, is64);
        int b = d >> BSHIFT;
        int pos = atomicAdd(&curw[w][b], 1);
        packed[wbase[b] + histw[w][b] + pos] = (s << BSHIFT) | (d & ((1 << BSHIFT) - 1));
    }
}

// ---------------- fine fill v2: one block per bucket. Self-builds the per-node
// CSR for its 1024 nodes: LDS histogram (LDS atomics) -> 1024-wide block scan ->
// writes rowptr/cnt -> scatters srclist via LDS cursors. Replaces the old
// global hist + 3 scan kernels.
__global__ __launch_bounds__(256) void finefill_kernel(
    const int* __restrict__ bstart,
    const int* __restrict__ packed,
    int* __restrict__ rowptr,
    int* __restrict__ cnt,
    int* __restrict__ srclist)
{
    __shared__ int lcnt[1 << BSHIFT];
    __shared__ int lsum[256];
    int b = blockIdx.x;
    int tid = threadIdx.x;
    int nbase = b << BSHIFT;
    int beg = bstart[b];
    int end = bstart[b + 1];

    for (int i = tid; i < (1 << BSHIFT); i += 256) lcnt[i] = 0;
    __syncthreads();

    // pass 1: in-bucket per-node histogram (LDS atomics)
    for (int j = beg + tid; j < end; j += 256)
        atomicAdd(&lcnt[packed[j] & ((1 << BSHIFT) - 1)], 1);
    __syncthreads();

    // 1024-wide exclusive scan: 4 elems/thread + 256-wide Hillis-Steele
    int i0 = tid * 4;
    int c0 = lcnt[i0], c1 = lcnt[i0 + 1], c2 = lcnt[i0 + 2], c3 = lcnt[i0 + 3];
    lsum[tid] = c0 + c1 + c2 + c3;
    __syncthreads();
    for (int off = 1; off < 256; off <<= 1) {
        int v = lsum[tid];
        if (tid >= off) v += lsum[tid - off];
        __syncthreads();
        lsum[tid] = v;
        __syncthreads();
    }
    int run = beg + ((tid == 0) ? 0 : lsum[tid - 1]);
    int r0 = run, r1 = r0 + c0, r2 = r1 + c1, r3 = r2 + c2;

    int n0 = nbase + i0;
    if (n0     < NT) { rowptr[n0]     = r0; cnt[n0]     = c0; }
    if (n0 + 1 < NT) { rowptr[n0 + 1] = r1; cnt[n0 + 1] = c1; }
    if (n0 + 2 < NT) { rowptr[n0 + 2] = r2; cnt[n0 + 2] = c2; }
    if (n0 + 3 < NT) { rowptr[n0 + 3] = r3; cnt[n0 + 3] = c3; }

    // convert lcnt to running cursors
    lcnt[i0] = r0; lcnt[i0 + 1] = r1; lcnt[i0 + 2] = r2; lcnt[i0 + 3] = r3;
    __syncthreads();

    // pass 2: scatter src ids (stores confined to this bucket's srclist range)
    for (int j = beg + tid; j < end; j += 256) {
        int p = packed[j];
        int dl = p & ((1 << BSHIFT) - 1);
        int pos = atomicAdd(&lcnt[dl], 1);
        srclist[pos] = p >> BSHIFT;
    }
}

// ---------------- gather: meanb[n] = mean over incoming edges of x[src]
// 4 lanes per node, 16 nodes per wave. Lane owns a fixed 16-elem (32B) segment of
// its node's row => no cross-lane reduction; 16 independent load chains per wave.
__global__ __launch_bounds__(256) void gather_mean(
    const unsigned short* __restrict__ x,
    const int* __restrict__ rowptr,
    const int* __restrict__ cnt,
    const int* __restrict__ srclist,
    unsigned short* __restrict__ meanb)
{
    int wid = (blockIdx.x * 256 + threadIdx.x) >> 6;   // wave id; NT = 17500*16 exactly
    int lane = threadIdx.x & 63;
    int g = lane >> 2;          // node group 0..15
    int sub = lane & 3;         // 16-elem segment 0..3
    int n = wid * 16 + g;
    if (n >= NT) return;
    int beg = rowptr[n];
    int deg = cnt[n];

    float acc[16];
    #pragma unroll
    for (int k = 0; k < 16; ++k) acc[k] = 0.f;

    for (int j0 = 0; j0 < deg; j0 += 4) {
        int e = j0 + sub;
        int sv = (e < deg) ? srclist[beg + e] : 0;    // 4 coalesced edge-id loads per group
        int cq = deg - j0; if (cq > 4) cq = 4;
        short8 r[4][2];
        #pragma unroll
        for (int q = 0; q < 4; ++q) {                 // 8 independent 16B loads in flight
            int s = __shfl(sv, (g << 2) | q);
            const short8* p = (const short8*)&x[(long)s * HD + sub * 16];
            r[q][0] = p[0];
            r[q][1] = p[1];
        }
        #pragma unroll
        for (int q = 0; q < 4; ++q) {
            if (q < cq) {
                #pragma unroll
                for (int k = 0; k < 8; ++k) {
                    acc[k]     += bfu2f((unsigned short)r[q][0][k]);
                    acc[k + 8] += bfu2f((unsigned short)r[q][1][k]);
                }
            }
        }
    }

    float rd = 1.0f / fmaxf((float)deg, 1.0f);
    short8 o0, o1;
    #pragma unroll
    for (int k = 0; k < 8; ++k) {
        o0[k] = (short)f2bf_raw(acc[k] * rd);
        o1[k] = (short)f2bf_raw(acc[k + 8] * rd);
    }
    short8* op = (short8*)&meanb[(long)n * HD + sub * 16];
    op[0] = o0;
    op[1] = o1;
}

// ---------------- combine: out = act( mean @ Wl.T + b + xin @ Wr.T )   [in-place: out may == xin]
template <bool RELU>
__global__ __launch_bounds__(256) void combine_kernel(
    const unsigned short* __restrict__ meanb,
    const unsigned short* __restrict__ xin,
    const void* __restrict__ Wl,
    const void* __restrict__ bias,
    const void* __restrict__ Wr,
    unsigned short* __restrict__ out,
    const int* __restrict__ flags)
{
    __shared__ short8 lWl8[HD * HD / 8];
    __shared__ short8 lWr8[HD * HD / 8];
    __shared__ short8 lmean8[HD * HD / 8];
    __shared__ short8 lx8[HD * HD / 8];
    __shared__ float lb[HD];
    unsigned short* lWl  = (unsigned short*)lWl8;
    unsigned short* lWr  = (unsigned short*)lWr8;
    unsigned short* lmean = (unsigned short*)lmean8;
    unsigned short* lx   = (unsigned short*)lx8;

    int tid = threadIdx.x;
    int isbf = flags[0];
    if (isbf) {
        const short8* wl8 = (const short8*)Wl;
        const short8* wr8 = (const short8*)Wr;
        for (int i = tid; i < HD * HD / 8; i += 256) { lWl8[i] = wl8[i]; lWr8[i] = wr8[i]; }
    } else {
        const floatx4* wlf = (const floatx4*)Wl;
        const floatx4* wrf = (const floatx4*)Wr;
        for (int i = tid; i < HD * HD / 8; i += 256) {
            floatx4 a = wlf[2 * i], b = wlf[2 * i + 1];
            short8 r;
            r[0]=(short)f2bf_raw(a[0]); r[1]=(short)f2bf_raw(a[1]); r[2]=(short)f2bf_raw(a[2]); r[3]=(short)f2bf_raw(a[3]);
            r[4]=(short)f2bf_raw(b[0]); r[5]=(short)f2bf_raw(b[1]); r[6]=(short)f2bf_raw(b[2]); r[7]=(short)f2bf_raw(b[3]);
            lWl8[i] = r;
            a = wrf[2 * i]; b = wrf[2 * i + 1];
            r[0]=(short)f2bf_raw(a[0]); r[1]=(short)f2bf_raw(a[1]); r[2]=(short)f2bf_raw(a[2]); r[3]=(short)f2bf_raw(a[3]);
            r[4]=(short)f2bf_raw(b[0]); r[5]=(short)f2bf_raw(b[1]); r[6]=(short)f2bf_raw(b[2]); r[7]=(short)f2bf_raw(b[3]);
            lWr8[i] = r;
        }
    }
    if (tid < HD) lb[tid] = ldf(bias, tid, isbf);

    int tile = blockIdx.x;                 // 64 nodes per tile; NT = 64*4375 exactly
    long base = (long)tile * HD * HD;
    const short8* mv = (const short8*)(meanb + base);
    const short8* xv = (const short8*)(xin + base);
    for (int i = tid; i < HD * HD / 8; i += 256) { lmean8[i] = mv[i]; lx8[i] = xv[i]; }
    __syncthreads();      // all reads of this tile's xin complete before any in-place write below

    int w = tid >> 6;
    int lane = tid & 63;
    int mrow = lane & 15;
    int quad = lane >> 4;

    short8 am0 = *(const short8*)&lmean[(w * 16 + mrow) * HD + quad * 8];
    short8 am1 = *(const short8*)&lmean[(w * 16 + mrow) * HD + 32 + quad * 8];
    short8 ax0 = *(const short8*)&lx[(w * 16 + mrow) * HD + quad * 8];
    short8 ax1 = *(const short8*)&lx[(w * 16 + mrow) * HD + 32 + quad * 8];

    floatx4 acc[4];
    #pragma unroll
    for (int ht = 0; ht < 4; ++ht) {
        int h = ht * 16 + mrow;
        short8 bl0 = *(const short8*)&lWl[h * HD + quad * 8];
        short8 bl1 = *(const short8*)&lWl[h * HD + 32 + quad * 8];
        short8 br0 = *(const short8*)&lWr[h * HD + quad * 8];
        short8 br1 = *(const short8*)&lWr[h * HD + 32 + quad * 8];
        floatx4 a = {0.f, 0.f, 0.f, 0.f};
        a = __builtin_amdgcn_mfma_f32_16x16x32_bf16(am0, bl0, a, 0, 0, 0);
        a = __builtin_amdgcn_mfma_f32_16x16x32_bf16(am1, bl1, a, 0, 0, 0);
        a = __builtin_amdgcn_mfma_f32_16x16x32_bf16(ax0, br0, a, 0, 0, 0);
        a = __builtin_amdgcn_mfma_f32_16x16x32_bf16(ax1, br1, a, 0, 0, 0);
        acc[ht] = a;
    }

    #pragma unroll
    for (int ht = 0; ht < 4; ++ht) {
        int h = ht * 16 + mrow;
        float bv = lb[h];
        #pragma unroll
        for (int r = 0; r < 4; ++r) {
            int node = w * 16 + quad * 4 + r;
            float v = acc[ht][r] + bv;
            if (RELU) v = fmaxf(v, 0.0f);
            out[base + node * HD + h] = f2bf_raw(v);
        }
    }
}

// ---------------- final: out[e] = dot(x2[u[e]], x2[NU + m[e]])
// 4 lanes per edge, 16 edges per wave; 16B vector loads; 2-step xor reduce.
__global__ __launch_bounds__(256) void dot_kernel(
    const unsigned short* __restrict__ x2,
    const int* __restrict__ eli,
    void* __restrict__ out,
    int EL,
    const int* __restrict__ flags)
{
    int wid = (blockIdx.x * 256 + threadIdx.x) >> 6;    // global wave id
    long base = (long)wid * 16;                          // first edge of this wave
    if (base >= EL) return;
    int lane = threadIdx.x & 63;
    int isbf = flags[0];
    int is64 = flags[1];

    // lanes 0..15 load u indices, lanes 16..31 load m indices (EL % 16 == 0)
    int idxv = 0;
    if (lane < 16)      idxv = ldidx(eli, base + lane, is64);
    else if (lane < 32) idxv = ldidx(eli, (long)EL + base + (lane - 16), is64);

    int e   = lane >> 2;          // edge slot 0..15
    int seg = lane & 3;           // 16-element segment of the 64-dim row
    int u = __shfl(idxv, e);
    int m = __shfl(idxv, 16 + e);

    const short8* up = (const short8*)(x2 + (long)u * HD + seg * 16);
    const short8* mp = (const short8*)(x2 + (long)(NU + m) * HD + seg * 16);
    short8 a0 = up[0], a1 = up[1];
    short8 b0 = mp[0], b1 = mp[1];

    float p = 0.f;
    #pragma unroll
    for (int j = 0; j < 8; ++j) {
        p += bfu2f((unsigned short)a0[j]) * bfu2f((unsigned short)b0[j]);
        p += bfu2f((unsigned short)a1[j]) * bfu2f((unsigned short)b1[j]);
    }
    p += __shfl_xor(p, 1);
    p += __shfl_xor(p, 2);

    if (seg == 0) {
        long g = base + e;
        if (isbf) ((unsigned short*)out)[g] = f2bf_raw(p);
        else      ((float*)out)[g] = p;
    }
}

extern "C" void kernel_launch(void* const* d_in, const int* in_sizes, int n_in,
                              void* d_out, int out_size, void* d_ws, size_t ws_size,
                              hipStream_t stream)
{
    const void* movie_x   = d_in[0];
    const void* user_emb  = d_in[1];
    const void* movie_emb = d_in[2];
    const void* lin_W     = d_in[3];
    const void* lin_b     = d_in[4];
    const void* W1l       = d_in[5];
    const void* b1        = d_in[6];
    const void* W1r       = d_in[7];
    const void* W2l       = d_in[8];
    const void* b2        = d_in[9];
    const void* W2r       = d_in[10];
    const int* ei  = (const int*)d_in[11];
    const int* eli = (const int*)d_in[12];
    int E  = in_sizes[11] / 2;
    int EL = in_sizes[12] / 2;

    char* w = (char*)d_ws;
    unsigned short* xb      = (unsigned short*)w;  w += (size_t)NT * HD * 2;  // 35.84 MB
    unsigned short* meanb   = (unsigned short*)w;  w += (size_t)NT * HD * 2;  // 35.84 MB
    int*            cnt     = (int*)w;             w += (size_t)NT * 4;
    int*            rowptr  = (int*)w;             w += (size_t)NT * 4;
    int*            srclist = (int*)w;             w += (size_t)E * 4;        // 5 MB
    int*            packed  = (int*)w;             w += (size_t)E * 4;        // 5 MB
    int*            bcnt    = (int*)w;             w += (size_t)(NBUCK + 1) * 4;
    int*            bstart  = (int*)w;             w += (size_t)(NBUCK + 1) * 4;
    int*            bfill   = (int*)w;             w += (size_t)NBUCK * 4;
    int*            flags   = (int*)w;

    const int user_blocks   = (NU * HD / 8) / 256;      // 6250 exactly
    const int movie_blocks  = NM / 16;                  // 5000: 4 waves/block x 4 movies/wave
    const int hist_blocks   = (E + HCHUNK - 1) / HCHUNK;
    const int bucket_blocks = (E + CHUNK - 1) / CHUNK;  // 611
    const int gather_blocks = ((NT / 16) * 64 + 255) / 256;  // 4375 (16 nodes/wave)
    const int tile_blocks   = NT / 64;                  // 4375
    const int dot_blocks    = ((EL + 15) / 16 + 3) / 4; // 7813

    probe_kernel<<<1, 64, 0, stream>>>(user_emb, ei, flags);

    prep_user<<<user_blocks, 256, 0, stream>>>(user_emb, xb, flags);
    prep_movie<<<movie_blocks, 256, 0, stream>>>(movie_x, movie_emb, lin_W, lin_b, xb, flags);

    // CSR build (once; reused by both layers) -- bucket-local, no global per-node atomics
    hipMemsetAsync(bcnt, 0, (size_t)(NBUCK + 1) * 4, stream);
    hipMemsetAsync(bfill, 0, (size_t)NBUCK * 4, stream);
    bucket_hist<<<hist_blocks, 256, 0, stream>>>(ei, E, bcnt, flags);
    bucket_scan<<<1, 256, 0, stream>>>(bcnt, bstart, E);
    bucket_kernel<<<bucket_blocks, 256, 0, stream>>>(ei, E, bstart, bfill, packed, flags);
    finefill_kernel<<<NBUCK, 256, 0, stream>>>(bstart, packed, rowptr, cnt, srclist);

    // layer 1
    gather_mean<<<gather_blocks, 256, 0, stream>>>(xb, rowptr, cnt, srclist, meanb);
    combine_kernel<true><<<tile_blocks, 256, 0, stream>>>(meanb, xb, W1l, b1, W1r, xb, flags);

    // layer 2
    gather_mean<<<gather_blocks, 256, 0, stream>>>(xb, rowptr, cnt, srclist, meanb);
    combine_kernel<false><<<tile_blocks, 256, 0, stream>>>(meanb, xb, W2l, b2, W2r, xb, flags);

    // final edge dot products
    dot_kernel<<<dot_blocks, 256, 0, stream>>>(xb, eli, d_out, EL, flags);
}

// Round 3
// 327.157 us; speedup vs baseline: 1.2697x; 1.0885x over previous
//
#include <hip/hip_runtime.h>
#include <hip/hip_bf16.h>

#define NU 200000
#define NM 80000
#define NT 280000   // NU + NM
#define HD 64
#define FM 20

#define BSHIFT 10
#define NBUCK ((NT + 1023) >> 10)   // 274 buckets of 1024 nodes
#define SCHUNK 4096                 // edges per hist/scatter block

typedef __attribute__((ext_vector_type(8))) short short8;
typedef __attribute__((ext_vector_type(4))) float floatx4;

__device__ __forceinline__ float bfu2f(unsigned short u) {
    union { unsigned int u; float f; } c; c.u = ((unsigned int)u) << 16; return c.f;
}

__device__ __forceinline__ unsigned short f2bf_raw(float f) {
    union { float f; unsigned int u; } c; c.f = f;
    unsigned int u = c.u + 0x7FFFu + ((c.u >> 16) & 1u);   // round-nearest-even
    return (unsigned short)(u >> 16);
}

__device__ __forceinline__ float ldf(const void* p, long i, int isbf) {
    return isbf ? bfu2f(((const unsigned short*)p)[i]) : ((const float*)p)[i];
}
__device__ __forceinline__ int ldidx(const int* p, long j, int is64) {
    return is64 ? p[2 * j] : p[j];
}

// ---------------- runtime dtype probe -> flags[0]=isbf16, flags[1]=isint64
__global__ void probe_kernel(const void* user_emb, const int* ei, int* flags) {
    int t = threadIdx.x;
    int bad = 0;
    for (int i = t; i < 128; i += 64) {
        unsigned short h = ((const unsigned short*)user_emb)[i];
        unsigned int e = (h >> 7) & 0xFF;
        if (e >= 135) bad = 1;               // |x| >= 256, or Inf/NaN -> not real bf16
    }
    unsigned long long mf = __ballot(bad != 0);
    int odd_nonzero = 0;
    if (t < 16 && ei[2 * t + 1] != 0) odd_nonzero = 1;
    unsigned long long mi = __ballot(odd_nonzero != 0);
    if (t == 0) {
        flags[0] = (mf == 0) ? 1 : 0;
        flags[1] = (mi == 0) ? 1 : 0;
    }
}

// ---------------- prep A: user rows, vectorized copy/convert (8 elems/thread)
__global__ __launch_bounds__(256) void prep_user(
    const void* __restrict__ user_emb,
    unsigned short* __restrict__ xb,
    const int* __restrict__ flags)
{
    long t = (long)blockIdx.x * 256 + threadIdx.x;        // t < NU*HD/8 = 1.6M exactly
    int isbf = flags[0];
    if (isbf) {
        ((short8*)xb)[t] = ((const short8*)user_emb)[t];
    } else {
        floatx4 a = ((const floatx4*)user_emb)[2 * t];
        floatx4 b = ((const floatx4*)user_emb)[2 * t + 1];
        short8 r;
        r[0] = (short)f2bf_raw(a[0]); r[1] = (short)f2bf_raw(a[1]);
        r[2] = (short)f2bf_raw(a[2]); r[3] = (short)f2bf_raw(a[3]);
        r[4] = (short)f2bf_raw(b[0]); r[5] = (short)f2bf_raw(b[1]);
        r[6] = (short)f2bf_raw(b[2]); r[7] = (short)f2bf_raw(b[3]);
        ((short8*)xb)[t] = r;
    }
}

// ---------------- prep B: movie rows, latency-optimized.
// One wave computes 4 movies. Lane h holds lin_W[h][0..19] in registers;
// movie_x row address is wave-uniform (scalarizes to s_load); no shfl chain,
// no LDS, no barrier. Split accumulators keep FMA chains short.
__global__ __launch_bounds__(256) void prep_movie(
    const void* __restrict__ movie_x,
    const void* __restrict__ movie_emb,
    const void* __restrict__ lin_W,
    const void* __restrict__ lin_b,
    unsigned short* __restrict__ xb,
    const int* __restrict__ flags)
{
    int isbf = flags[0];
    int tid = threadIdx.x;
    int lane = tid & 63;
    int wave = blockIdx.x * 4 + (tid >> 6);
    int m0 = __builtin_amdgcn_readfirstlane(wave << 2);   // 4 movies per wave
    if (m0 >= NM) return;

    // per-lane weight row lin_W[lane][0..19]; dword-granular loads
    float wr[FM];
    if (isbf) {
        const unsigned int* p = (const unsigned int*)((const unsigned short*)lin_W + (long)lane * FM);
        #pragma unroll
        for (int i = 0; i < FM / 2; ++i) {
            unsigned int u = p[i];
            wr[2 * i]     = bfu2f((unsigned short)(u & 0xFFFFu));
            wr[2 * i + 1] = bfu2f((unsigned short)(u >> 16));
        }
    } else {
        const floatx4* p = (const floatx4*)((const float*)lin_W + (long)lane * FM);  // 80B rows, 16B-aligned
        #pragma unroll
        for (int i = 0; i < FM / 4; ++i) {
            floatx4 v = p[i];
            wr[4 * i] = v[0]; wr[4 * i + 1] = v[1]; wr[4 * i + 2] = v[2]; wr[4 * i + 3] = v[3];
        }
    }
    float bias = ldf(lin_b, lane, isbf);

    #pragma unroll
    for (int mm = 0; mm < 4; ++mm) {
        int m = m0 + mm;
        float a0 = bias + ldf(movie_emb, (long)m * HD + lane, isbf);  // coalesced 256B/wave
        float a1 = 0.f, a2 = 0.f, a3 = 0.f;
        if (isbf) {
            const unsigned int* mr = (const unsigned int*)((const unsigned short*)movie_x + (long)m * FM);
            #pragma unroll
            for (int kk = 0; kk < FM / 2; ++kk) {                     // uniform-address dword loads
                unsigned int u = mr[kk];
                float x0 = bfu2f((unsigned short)(u & 0xFFFFu));
                float x1 = bfu2f((unsigned short)(u >> 16));
                if (kk & 1) { a2 += x0 * wr[2 * kk]; a3 += x1 * wr[2 * kk + 1]; }
                else        { a0 += x0 * wr[2 * kk]; a1 += x1 * wr[2 * kk + 1]; }
            }
        } else {
            const float* mr = (const float*)movie_x + (long)m * FM;   // uniform address -> s_load
            #pragma unroll
            for (int k = 0; k < FM; k += 4) {
                a0 += mr[k]     * wr[k];
                a1 += mr[k + 1] * wr[k + 1];
                a2 += mr[k + 2] * wr[k + 2];
                a3 += mr[k + 3] * wr[k + 3];
            }
        }
        xb[(long)(NU + m) * HD + lane] = f2bf_raw((a0 + a1) + (a2 + a3));
    }
}

// ---------------- CSR build v3: atomic-free scatter via 2D histogram scan ----
// blk_hist: per-block LDS bucket histogram -> blkhist[blk][bucket] (plain stores)
__global__ __launch_bounds__(512) void blk_hist(
    const int* __restrict__ ei, int E,
    int* __restrict__ blkhist,
    const int* __restrict__ flags)
{
    __shared__ int h[NBUCK];
    int tid = threadIdx.x;
    for (int i = tid; i < NBUCK; i += 512) h[i] = 0;
    __syncthreads();
    int is64 = flags[1];
    long e0 = (long)blockIdx.x * SCHUNK;
    long e1 = e0 + SCHUNK; if (e1 > E) e1 = E;
    for (long j = e0 + tid; j < e1; j += 512) {
        int d = ldidx(ei, (long)E + j, is64);
        atomicAdd(&h[d >> BSHIFT], 1);
    }
    __syncthreads();
    long obase = (long)blockIdx.x * NBUCK;
    for (int i = tid; i < NBUCK; i += 512) blkhist[obase + i] = h[i];
}

// col_scan: one block per bucket b. Exclusive prefix over blocks, in place;
// emits bucket total to bcnt[b]. No atomics. Supports NSB <= 2048.
__global__ __launch_bounds__(256) void col_scan(
    int* __restrict__ blkhist, int NSB,
    int* __restrict__ bcnt)
{
    __shared__ int larr[2048];
    __shared__ int lsum[256];
    int b = blockIdx.x;
    int t = threadIdx.x;
    for (int i = t; i < NSB; i += 256) larr[i] = blkhist[(long)i * NBUCK + b];
    __syncthreads();
    int C = (NSB + 255) >> 8;
    int beg = t * C;
    int end = beg + C; if (end > NSB) end = NSB; if (beg > NSB) beg = NSB;
    int s = 0;
    for (int i = beg; i < end; ++i) s += larr[i];
    lsum[t] = s;
    __syncthreads();
    for (int off = 1; off < 256; off <<= 1) {
        int v = lsum[t];
        if (t >= off) v += lsum[t - off];
        __syncthreads();
        lsum[t] = v;
        __syncthreads();
    }
    int run = (t == 0) ? 0 : lsum[t - 1];
    for (int i = beg; i < end; ++i) {
        int v = larr[i];
        blkhist[(long)i * NBUCK + b] = run;   // exclusive offset of block i in bucket b
        run += v;
    }
    if (t == 0) bcnt[b] = lsum[255];
}

// ---------------- scan 274 bucket counts -> bstart[NBUCK+1] (exclusive, bstart[NBUCK]=E)
__global__ __launch_bounds__(256) void bucket_scan(
    const int* __restrict__ bcnt, int* __restrict__ bstart, int E)
{
    __shared__ int s[256];
    int t = threadIdx.x;
    int a0 = (2 * t     < NBUCK) ? bcnt[2 * t]     : 0;
    int a1 = (2 * t + 1 < NBUCK) ? bcnt[2 * t + 1] : 0;
    s[t] = a0 + a1;
    __syncthreads();
    for (int off = 1; off < 256; off <<= 1) {
        int v = s[t];
        if (t >= off) v += s[t - off];
        __syncthreads();
        s[t] = v;
        __syncthreads();
    }
    int run = (t == 0) ? 0 : s[t - 1];
    if (2 * t     < NBUCK) bstart[2 * t]     = run;
    if (2 * t + 1 < NBUCK) bstart[2 * t + 1] = run + a0;
    if (t == 0) bstart[NBUCK] = E;
}

// scatter: deterministic base per (block,bucket) from the scans; LDS cursors only.
// packed entry: (src<<10) | (dst&1023).
__global__ __launch_bounds__(512) void scatter_kernel(
    const int* __restrict__ ei, int E,
    const int* __restrict__ bstart,
    const int* __restrict__ blkhist,
    int* __restrict__ packed,
    const int* __restrict__ flags)
{
    __shared__ int cur[NBUCK];
    int tid = threadIdx.x;
    long obase = (long)blockIdx.x * NBUCK;
    for (int i = tid; i < NBUCK; i += 512) cur[i] = bstart[i] + blkhist[obase + i];
    __syncthreads();
    int is64 = flags[1];
    long e0 = (long)blockIdx.x * SCHUNK;
    long e1 = e0 + SCHUNK; if (e1 > E) e1 = E;
    for (long j = e0 + tid; j < e1; j += 512) {
        int s = ldidx(ei, j, is64);
        int d = ldidx(ei, (long)E + j, is64);
        int b = d >> BSHIFT;
        int pos = atomicAdd(&cur[b], 1);
        packed[pos] = (s << BSHIFT) | (d & ((1 << BSHIFT) - 1));
    }
}

// ---------------- fine fill: one block per bucket. Self-builds the per-node
// CSR for its 1024 nodes: LDS histogram (LDS atomics) -> 1024-wide block scan ->
// writes rowptr/cnt -> scatters srclist via LDS cursors.
__global__ __launch_bounds__(256) void finefill_kernel(
    const int* __restrict__ bstart,
    const int* __restrict__ packed,
    int* __restrict__ rowptr,
    int* __restrict__ cnt,
    int* __restrict__ srclist)
{
    __shared__ int lcnt[1 << BSHIFT];
    __shared__ int lsum[256];
    int b = blockIdx.x;
    int tid = threadIdx.x;
    int nbase = b << BSHIFT;
    int beg = bstart[b];
    int end = bstart[b + 1];

    for (int i = tid; i < (1 << BSHIFT); i += 256) lcnt[i] = 0;
    __syncthreads();

    // pass 1: in-bucket per-node histogram (LDS atomics)
    for (int j = beg + tid; j < end; j += 256)
        atomicAdd(&lcnt[packed[j] & ((1 << BSHIFT) - 1)], 1);
    __syncthreads();

    // 1024-wide exclusive scan: 4 elems/thread + 256-wide Hillis-Steele
    int i0 = tid * 4;
    int c0 = lcnt[i0], c1 = lcnt[i0 + 1], c2 = lcnt[i0 + 2], c3 = lcnt[i0 + 3];
    lsum[tid] = c0 + c1 + c2 + c3;
    __syncthreads();
    for (int off = 1; off < 256; off <<= 1) {
        int v = lsum[tid];
        if (tid >= off) v += lsum[tid - off];
        __syncthreads();
        lsum[tid] = v;
        __syncthreads();
    }
    int run = beg + ((tid == 0) ? 0 : lsum[tid - 1]);
    int r0 = run, r1 = r0 + c0, r2 = r1 + c1, r3 = r2 + c2;

    int n0 = nbase + i0;
    if (n0     < NT) { rowptr[n0]     = r0; cnt[n0]     = c0; }
    if (n0 + 1 < NT) { rowptr[n0 + 1] = r1; cnt[n0 + 1] = c1; }
    if (n0 + 2 < NT) { rowptr[n0 + 2] = r2; cnt[n0 + 2] = c2; }
    if (n0 + 3 < NT) { rowptr[n0 + 3] = r3; cnt[n0 + 3] = c3; }

    // convert lcnt to running cursors
    lcnt[i0] = r0; lcnt[i0 + 1] = r1; lcnt[i0 + 2] = r2; lcnt[i0 + 3] = r3;
    __syncthreads();

    // pass 2: scatter src ids (stores confined to this bucket's srclist range)
    for (int j = beg + tid; j < end; j += 256) {
        int p = packed[j];
        int dl = p & ((1 << BSHIFT) - 1);
        int pos = atomicAdd(&lcnt[dl], 1);
        srclist[pos] = p >> BSHIFT;
    }
}

// ---------------- gather: meanb[n] = mean over incoming edges of x[src]
// 4 lanes per node, 16 nodes per wave. Lane owns a fixed 16-elem (32B) segment of
// its node's row => no cross-lane reduction; 16 independent load chains per wave.
__global__ __launch_bounds__(256) void gather_mean(
    const unsigned short* __restrict__ x,
    const int* __restrict__ rowptr,
    const int* __restrict__ cnt,
    const int* __restrict__ srclist,
    unsigned short* __restrict__ meanb)
{
    int wid = (blockIdx.x * 256 + threadIdx.x) >> 6;   // wave id; NT = 17500*16 exactly
    int lane = threadIdx.x & 63;
    int g = lane >> 2;          // node group 0..15
    int sub = lane & 3;         // 16-elem segment 0..3
    int n = wid * 16 + g;
    if (n >= NT) return;
    int beg = rowptr[n];
    int deg = cnt[n];

    float acc[16];
    #pragma unroll
    for (int k = 0; k < 16; ++k) acc[k] = 0.f;

    for (int j0 = 0; j0 < deg; j0 += 4) {
        int e = j0 + sub;
        int sv = (e < deg) ? srclist[beg + e] : 0;    // 4 coalesced edge-id loads per group
        int cq = deg - j0; if (cq > 4) cq = 4;
        short8 r[4][2];
        #pragma unroll
        for (int q = 0; q < 4; ++q) {                 // 8 independent 16B loads in flight
            int s = __shfl(sv, (g << 2) | q);
            const short8* p = (const short8*)&x[(long)s * HD + sub * 16];
            r[q][0] = p[0];
            r[q][1] = p[1];
        }
        #pragma unroll
        for (int q = 0; q < 4; ++q) {
            if (q < cq) {
                #pragma unroll
                for (int k = 0; k < 8; ++k) {
                    acc[k]     += bfu2f((unsigned short)r[q][0][k]);
                    acc[k + 8] += bfu2f((unsigned short)r[q][1][k]);
                }
            }
        }
    }

    float rd = 1.0f / fmaxf((float)deg, 1.0f);
    short8 o0, o1;
    #pragma unroll
    for (int k = 0; k < 8; ++k) {
        o0[k] = (short)f2bf_raw(acc[k] * rd);
        o1[k] = (short)f2bf_raw(acc[k + 8] * rd);
    }
    short8* op = (short8*)&meanb[(long)n * HD + sub * 16];
    op[0] = o0;
    op[1] = o1;
}

// ---------------- combine: out = act( mean @ Wl.T + b + xin @ Wr.T )   [in-place: out may == xin]
template <bool RELU>
__global__ __launch_bounds__(256) void combine_kernel(
    const unsigned short* __restrict__ meanb,
    const unsigned short* __restrict__ xin,
    const void* __restrict__ Wl,
    const void* __restrict__ bias,
    const void* __restrict__ Wr,
    unsigned short* __restrict__ out,
    const int* __restrict__ flags)
{
    __shared__ short8 lWl8[HD * HD / 8];
    __shared__ short8 lWr8[HD * HD / 8];
    __shared__ short8 lmean8[HD * HD / 8];
    __shared__ short8 lx8[HD * HD / 8];
    __shared__ float lb[HD];
    unsigned short* lWl  = (unsigned short*)lWl8;
    unsigned short* lWr  = (unsigned short*)lWr8;
    unsigned short* lmean = (unsigned short*)lmean8;
    unsigned short* lx   = (unsigned short*)lx8;

    int tid = threadIdx.x;
    int isbf = flags[0];
    if (isbf) {
        const short8* wl8 = (const short8*)Wl;
        const short8* wr8 = (const short8*)Wr;
        for (int i = tid; i < HD * HD / 8; i += 256) { lWl8[i] = wl8[i]; lWr8[i] = wr8[i]; }
    } else {
        const floatx4* wlf = (const floatx4*)Wl;
        const floatx4* wrf = (const floatx4*)Wr;
        for (int i = tid; i < HD * HD / 8; i += 256) {
            floatx4 a = wlf[2 * i], b = wlf[2 * i + 1];
            short8 r;
            r[0]=(short)f2bf_raw(a[0]); r[1]=(short)f2bf_raw(a[1]); r[2]=(short)f2bf_raw(a[2]); r[3]=(short)f2bf_raw(a[3]);
            r[4]=(short)f2bf_raw(b[0]); r[5]=(short)f2bf_raw(b[1]); r[6]=(short)f2bf_raw(b[2]); r[7]=(short)f2bf_raw(b[3]);
            lWl8[i] = r;
            a = wrf[2 * i]; b = wrf[2 * i + 1];
            r[0]=(short)f2bf_raw(a[0]); r[1]=(short)f2bf_raw(a[1]); r[2]=(short)f2bf_raw(a[2]); r[3]=(short)f2bf_raw(a[3]);
            r[4]=(short)f2bf_raw(b[0]); r[5]=(short)f2bf_raw(b[1]); r[6]=(short)f2bf_raw(b[2]); r[7]=(short)f2bf_raw(b[3]);
            lWr8[i] = r;
        }
    }
    if (tid < HD) lb[tid] = ldf(bias, tid, isbf);

    int tile = blockIdx.x;                 // 64 nodes per tile; NT = 64*4375 exactly
    long base = (long)tile * HD * HD;
    const short8* mv = (const short8*)(meanb + base);
    const short8* xv = (const short8*)(xin + base);
    for (int i = tid; i < HD * HD / 8; i += 256) { lmean8[i] = mv[i]; lx8[i] = xv[i]; }
    __syncthreads();      // all reads of this tile's xin complete before any in-place write below

    int w = tid >> 6;
    int lane = tid & 63;
    int mrow = lane & 15;
    int quad = lane >> 4;

    short8 am0 = *(const short8*)&lmean[(w * 16 + mrow) * HD + quad * 8];
    short8 am1 = *(const short8*)&lmean[(w * 16 + mrow) * HD + 32 + quad * 8];
    short8 ax0 = *(const short8*)&lx[(w * 16 + mrow) * HD + quad * 8];
    short8 ax1 = *(const short8*)&lx[(w * 16 + mrow) * HD + 32 + quad * 8];

    floatx4 acc[4];
    #pragma unroll
    for (int ht = 0; ht < 4; ++ht) {
        int h = ht * 16 + mrow;
        short8 bl0 = *(const short8*)&lWl[h * HD + quad * 8];
        short8 bl1 = *(const short8*)&lWl[h * HD + 32 + quad * 8];
        short8 br0 = *(const short8*)&lWr[h * HD + quad * 8];
        short8 br1 = *(const short8*)&lWr[h * HD + 32 + quad * 8];
        floatx4 a = {0.f, 0.f, 0.f, 0.f};
        a = __builtin_amdgcn_mfma_f32_16x16x32_bf16(am0, bl0, a, 0, 0, 0);
        a = __builtin_amdgcn_mfma_f32_16x16x32_bf16(am1, bl1, a, 0, 0, 0);
        a = __builtin_amdgcn_mfma_f32_16x16x32_bf16(ax0, br0, a, 0, 0, 0);
        a = __builtin_amdgcn_mfma_f32_16x16x32_bf16(ax1, br1, a, 0, 0, 0);
        acc[ht] = a;
    }

    #pragma unroll
    for (int ht = 0; ht < 4; ++ht) {
        int h = ht * 16 + mrow;
        float bv = lb[h];
        #pragma unroll
        for (int r = 0; r < 4; ++r) {
            int node = w * 16 + quad * 4 + r;
            float v = acc[ht][r] + bv;
            if (RELU) v = fmaxf(v, 0.0f);
            out[base + node * HD + h] = f2bf_raw(v);
        }
    }
}

// ---------------- final: out[e] = dot(x2[u[e]], x2[NU + m[e]])
// 4 lanes per edge, 16 edges per wave; 16B vector loads; 2-step xor reduce.
__global__ __launch_bounds__(256) void dot_kernel(
    const unsigned short* __restrict__ x2,
    const int* __restrict__ eli,
    void* __restrict__ out,
    int EL,
    const int* __restrict__ flags)
{
    int wid = (blockIdx.x * 256 + threadIdx.x) >> 6;    // global wave id
    long base = (long)wid * 16;                          // first edge of this wave
    if (base >= EL) return;
    int lane = threadIdx.x & 63;
    int isbf = flags[0];
    int is64 = flags[1];

    // lanes 0..15 load u indices, lanes 16..31 load m indices (EL % 16 == 0)
    int idxv = 0;
    if (lane < 16)      idxv = ldidx(eli, base + lane, is64);
    else if (lane < 32) idxv = ldidx(eli, (long)EL + base + (lane - 16), is64);

    int e   = lane >> 2;          // edge slot 0..15
    int seg = lane & 3;           // 16-element segment of the 64-dim row
    int u = __shfl(idxv, e);
    int m = __shfl(idxv, 16 + e);

    const short8* up = (const short8*)(x2 + (long)u * HD + seg * 16);
    const short8* mp = (const short8*)(x2 + (long)(NU + m) * HD + seg * 16);
    short8 a0 = up[0], a1 = up[1];
    short8 b0 = mp[0], b1 = mp[1];

    float p = 0.f;
    #pragma unroll
    for (int j = 0; j < 8; ++j) {
        p += bfu2f((unsigned short)a0[j]) * bfu2f((unsigned short)b0[j]);
        p += bfu2f((unsigned short)a1[j]) * bfu2f((unsigned short)b1[j]);
    }
    p += __shfl_xor(p, 1);
    p += __shfl_xor(p, 2);

    if (seg == 0) {
        long g = base + e;
        if (isbf) ((unsigned short*)out)[g] = f2bf_raw(p);
        else      ((float*)out)[g] = p;
    }
}

extern "C" void kernel_launch(void* const* d_in, const int* in_sizes, int n_in,
                              void* d_out, int out_size, void* d_ws, size_t ws_size,
                              hipStream_t stream)
{
    const void* movie_x   = d_in[0];
    const void* user_emb  = d_in[1];
    const void* movie_emb = d_in[2];
    const void* lin_W     = d_in[3];
    const void* lin_b     = d_in[4];
    const void* W1l       = d_in[5];
    const void* b1        = d_in[6];
    const void* W1r       = d_in[7];
    const void* W2l       = d_in[8];
    const void* b2        = d_in[9];
    const void* W2r       = d_in[10];
    const int* ei  = (const int*)d_in[11];
    const int* eli = (const int*)d_in[12];
    int E  = in_sizes[11] / 2;
    int EL = in_sizes[12] / 2;

    const int NSB = (E + SCHUNK - 1) / SCHUNK;          // hist/scatter blocks (306)

    char* w = (char*)d_ws;
    unsigned short* xb      = (unsigned short*)w;  w += (size_t)NT * HD * 2;  // 35.84 MB
    unsigned short* meanb   = (unsigned short*)w;  w += (size_t)NT * HD * 2;  // 35.84 MB
    int*            cnt     = (int*)w;             w += (size_t)NT * 4;
    int*            rowptr  = (int*)w;             w += (size_t)NT * 4;
    int*            srclist = (int*)w;             w += (size_t)E * 4;        // 5 MB
    int*            packed  = (int*)w;             w += (size_t)E * 4;        // 5 MB
    int*            bcnt    = (int*)w;             w += (size_t)(NBUCK + 1) * 4;
    int*            bstart  = (int*)w;             w += (size_t)(NBUCK + 1) * 4;
    int*            blkhist = (int*)w;             w += (size_t)NSB * NBUCK * 4;  // ~335 KB
    int*            flags   = (int*)w;

    const int user_blocks   = (NU * HD / 8) / 256;      // 6250 exactly
    const int movie_blocks  = NM / 16;                  // 5000: 4 waves/block x 4 movies/wave
    const int gather_blocks = ((NT / 16) * 64 + 255) / 256;  // 4375 (16 nodes/wave)
    const int tile_blocks   = NT / 64;                  // 4375
    const int dot_blocks    = ((EL + 15) / 16 + 3) / 4; // 7813

    probe_kernel<<<1, 64, 0, stream>>>(user_emb, ei, flags);

    prep_user<<<user_blocks, 256, 0, stream>>>(user_emb, xb, flags);
    prep_movie<<<movie_blocks, 256, 0, stream>>>(movie_x, movie_emb, lin_W, lin_b, xb, flags);

    // CSR build (once; reused by both layers) -- fully atomic-free global path
    blk_hist<<<NSB, 512, 0, stream>>>(ei, E, blkhist, flags);
    col_scan<<<NBUCK, 256, 0, stream>>>(blkhist, NSB, bcnt);
    bucket_scan<<<1, 256, 0, stream>>>(bcnt, bstart, E);
    scatter_kernel<<<NSB, 512, 0, stream>>>(ei, E, bstart, blkhist, packed, flags);
    finefill_kernel<<<NBUCK, 256, 0, stream>>>(bstart, packed, rowptr, cnt, srclist);

    // layer 1
    gather_mean<<<gather_blocks, 256, 0, stream>>>(xb, rowptr, cnt, srclist, meanb);
    combine_kernel<true><<<tile_blocks, 256, 0, stream>>>(meanb, xb, W1l, b1, W1r, xb, flags);

    // layer 2
    gather_mean<<<gather_blocks, 256, 0, stream>>>(xb, rowptr, cnt, srclist, meanb);
    combine_kernel<false><<<tile_blocks, 256, 0, stream>>>(meanb, xb, W2l, b2, W2r, xb, flags);

    // final edge dot products
    dot_kernel<<<dot_blocks, 256, 0, stream>>>(xb, eli, d_out, EL, flags);
}

// Round 4
// 305.745 us; speedup vs baseline: 1.3586x; 1.0700x over previous
//
#include <hip/hip_runtime.h>
#include <hip/hip_bf16.h>

#define NU 200000
#define NM 80000
#define NT 280000   // NU + NM
#define HD 64
#define FM 20

#define BSHIFT 10
#define NBUCK ((NT + 1023) >> 10)   // 274 buckets of 1024 nodes
#define SCHUNK 4096                 // edges per hist/scatter block

typedef __attribute__((ext_vector_type(8))) short short8;
typedef __attribute__((ext_vector_type(4))) float floatx4;

__device__ __forceinline__ float bfu2f(unsigned short u) {
    union { unsigned int u; float f; } c; c.u = ((unsigned int)u) << 16; return c.f;
}

__device__ __forceinline__ unsigned short f2bf_raw(float f) {
    union { float f; unsigned int u; } c; c.f = f;
    unsigned int u = c.u + 0x7FFFu + ((c.u >> 16) & 1u);   // round-nearest-even
    return (unsigned short)(u >> 16);
}

__device__ __forceinline__ float ldf(const void* p, long i, int isbf) {
    return isbf ? bfu2f(((const unsigned short*)p)[i]) : ((const float*)p)[i];
}
__device__ __forceinline__ int ldidx(const int* p, long j, int is64) {
    return is64 ? p[2 * j] : p[j];
}

// ---------------- runtime dtype probe -> flags[0]=isbf16, flags[1]=isint64
__global__ void probe_kernel(const void* user_emb, const int* ei, int* flags) {
    int t = threadIdx.x;
    int bad = 0;
    for (int i = t; i < 128; i += 64) {
        unsigned short h = ((const unsigned short*)user_emb)[i];
        unsigned int e = (h >> 7) & 0xFF;
        if (e >= 135) bad = 1;               // |x| >= 256, or Inf/NaN -> not real bf16
    }
    unsigned long long mf = __ballot(bad != 0);
    int odd_nonzero = 0;
    if (t < 16 && ei[2 * t + 1] != 0) odd_nonzero = 1;
    unsigned long long mi = __ballot(odd_nonzero != 0);
    if (t == 0) {
        flags[0] = (mf == 0) ? 1 : 0;
        flags[1] = (mi == 0) ? 1 : 0;
    }
}

// ---------------- prep A: user rows, vectorized copy/convert (8 elems/thread)
__global__ __launch_bounds__(256) void prep_user(
    const void* __restrict__ user_emb,
    unsigned short* __restrict__ xb,
    const int* __restrict__ flags)
{
    long t = (long)blockIdx.x * 256 + threadIdx.x;        // t < NU*HD/8 = 1.6M exactly
    int isbf = flags[0];
    if (isbf) {
        ((short8*)xb)[t] = ((const short8*)user_emb)[t];
    } else {
        floatx4 a = ((const floatx4*)user_emb)[2 * t];
        floatx4 b = ((const floatx4*)user_emb)[2 * t + 1];
        short8 r;
        r[0] = (short)f2bf_raw(a[0]); r[1] = (short)f2bf_raw(a[1]);
        r[2] = (short)f2bf_raw(a[2]); r[3] = (short)f2bf_raw(a[3]);
        r[4] = (short)f2bf_raw(b[0]); r[5] = (short)f2bf_raw(b[1]);
        r[6] = (short)f2bf_raw(b[2]); r[7] = (short)f2bf_raw(b[3]);
        ((short8*)xb)[t] = r;
    }
}

// ---------------- prep B: movie rows, latency-optimized.
// One wave computes 4 movies. Lane h holds lin_W[h][0..19] in registers;
// movie_x row address is wave-uniform (scalarizes to s_load); no shfl chain,
// no LDS, no barrier. Split accumulators keep FMA chains short.
__global__ __launch_bounds__(256) void prep_movie(
    const void* __restrict__ movie_x,
    const void* __restrict__ movie_emb,
    const void* __restrict__ lin_W,
    const void* __restrict__ lin_b,
    unsigned short* __restrict__ xb,
    const int* __restrict__ flags)
{
    int isbf = flags[0];
    int tid = threadIdx.x;
    int lane = tid & 63;
    int wave = blockIdx.x * 4 + (tid >> 6);
    int m0 = __builtin_amdgcn_readfirstlane(wave << 2);   // 4 movies per wave
    if (m0 >= NM) return;

    // per-lane weight row lin_W[lane][0..19]; dword-granular loads
    float wr[FM];
    if (isbf) {
        const unsigned int* p = (const unsigned int*)((const unsigned short*)lin_W + (long)lane * FM);
        #pragma unroll
        for (int i = 0; i < FM / 2; ++i) {
            unsigned int u = p[i];
            wr[2 * i]     = bfu2f((unsigned short)(u & 0xFFFFu));
            wr[2 * i + 1] = bfu2f((unsigned short)(u >> 16));
        }
    } else {
        const floatx4* p = (const floatx4*)((const float*)lin_W + (long)lane * FM);  // 80B rows, 16B-aligned
        #pragma unroll
        for (int i = 0; i < FM / 4; ++i) {
            floatx4 v = p[i];
            wr[4 * i] = v[0]; wr[4 * i + 1] = v[1]; wr[4 * i + 2] = v[2]; wr[4 * i + 3] = v[3];
        }
    }
    float bias = ldf(lin_b, lane, isbf);

    #pragma unroll
    for (int mm = 0; mm < 4; ++mm) {
        int m = m0 + mm;
        float a0 = bias + ldf(movie_emb, (long)m * HD + lane, isbf);  // coalesced 256B/wave
        float a1 = 0.f, a2 = 0.f, a3 = 0.f;
        if (isbf) {
            const unsigned int* mr = (const unsigned int*)((const unsigned short*)movie_x + (long)m * FM);
            #pragma unroll
            for (int kk = 0; kk < FM / 2; ++kk) {                     // uniform-address dword loads
                unsigned int u = mr[kk];
                float x0 = bfu2f((unsigned short)(u & 0xFFFFu));
                float x1 = bfu2f((unsigned short)(u >> 16));
                if (kk & 1) { a2 += x0 * wr[2 * kk]; a3 += x1 * wr[2 * kk + 1]; }
                else        { a0 += x0 * wr[2 * kk]; a1 += x1 * wr[2 * kk + 1]; }
            }
        } else {
            const float* mr = (const float*)movie_x + (long)m * FM;   // uniform address -> s_load
            #pragma unroll
            for (int k = 0; k < FM; k += 4) {
                a0 += mr[k]     * wr[k];
                a1 += mr[k + 1] * wr[k + 1];
                a2 += mr[k + 2] * wr[k + 2];
                a3 += mr[k + 3] * wr[k + 3];
            }
        }
        xb[(long)(NU + m) * HD + lane] = f2bf_raw((a0 + a1) + (a2 + a3));
    }
}

// ---------------- CSR build v3: atomic-free scatter via 2D histogram scan ----
// blk_hist: per-block LDS bucket histogram -> blkhist[blk][bucket] (plain stores)
__global__ __launch_bounds__(512) void blk_hist(
    const int* __restrict__ ei, int E,
    int* __restrict__ blkhist,
    const int* __restrict__ flags)
{
    __shared__ int h[NBUCK];
    int tid = threadIdx.x;
    for (int i = tid; i < NBUCK; i += 512) h[i] = 0;
    __syncthreads();
    int is64 = flags[1];
    long e0 = (long)blockIdx.x * SCHUNK;
    long e1 = e0 + SCHUNK; if (e1 > E) e1 = E;
    for (long j = e0 + tid; j < e1; j += 512) {
        int d = ldidx(ei, (long)E + j, is64);
        atomicAdd(&h[d >> BSHIFT], 1);
    }
    __syncthreads();
    long obase = (long)blockIdx.x * NBUCK;
    for (int i = tid; i < NBUCK; i += 512) blkhist[obase + i] = h[i];
}

// col_scan: one block per bucket b. Exclusive prefix over blocks, in place;
// emits bucket total to bcnt[b]. No atomics. Supports NSB <= 2048.
__global__ __launch_bounds__(256) void col_scan(
    int* __restrict__ blkhist, int NSB,
    int* __restrict__ bcnt)
{
    __shared__ int larr[2048];
    __shared__ int lsum[256];
    int b = blockIdx.x;
    int t = threadIdx.x;
    for (int i = t; i < NSB; i += 256) larr[i] = blkhist[(long)i * NBUCK + b];
    __syncthreads();
    int C = (NSB + 255) >> 8;
    int beg = t * C;
    int end = beg + C; if (end > NSB) end = NSB; if (beg > NSB) beg = NSB;
    int s = 0;
    for (int i = beg; i < end; ++i) s += larr[i];
    lsum[t] = s;
    __syncthreads();
    for (int off = 1; off < 256; off <<= 1) {
        int v = lsum[t];
        if (t >= off) v += lsum[t - off];
        __syncthreads();
        lsum[t] = v;
        __syncthreads();
    }
    int run = (t == 0) ? 0 : lsum[t - 1];
    for (int i = beg; i < end; ++i) {
        int v = larr[i];
        blkhist[(long)i * NBUCK + b] = run;   // exclusive offset of block i in bucket b
        run += v;
    }
    if (t == 0) bcnt[b] = lsum[255];
}

// ---------------- scan 274 bucket counts -> bstart[NBUCK+1] (exclusive, bstart[NBUCK]=E)
__global__ __launch_bounds__(256) void bucket_scan(
    const int* __restrict__ bcnt, int* __restrict__ bstart, int E)
{
    __shared__ int s[256];
    int t = threadIdx.x;
    int a0 = (2 * t     < NBUCK) ? bcnt[2 * t]     : 0;
    int a1 = (2 * t + 1 < NBUCK) ? bcnt[2 * t + 1] : 0;
    s[t] = a0 + a1;
    __syncthreads();
    for (int off = 1; off < 256; off <<= 1) {
        int v = s[t];
        if (t >= off) v += s[t - off];
        __syncthreads();
        s[t] = v;
        __syncthreads();
    }
    int run = (t == 0) ? 0 : s[t - 1];
    if (2 * t     < NBUCK) bstart[2 * t]     = run;
    if (2 * t + 1 < NBUCK) bstart[2 * t + 1] = run + a0;
    if (t == 0) bstart[NBUCK] = E;
}

// scatter: deterministic base per (block,bucket) from the scans; LDS cursors only.
// packed entry: (src<<10) | (dst&1023).
__global__ __launch_bounds__(512) void scatter_kernel(
    const int* __restrict__ ei, int E,
    const int* __restrict__ bstart,
    const int* __restrict__ blkhist,
    int* __restrict__ packed,
    const int* __restrict__ flags)
{
    __shared__ int cur[NBUCK];
    int tid = threadIdx.x;
    long obase = (long)blockIdx.x * NBUCK;
    for (int i = tid; i < NBUCK; i += 512) cur[i] = bstart[i] + blkhist[obase + i];
    __syncthreads();
    int is64 = flags[1];
    long e0 = (long)blockIdx.x * SCHUNK;
    long e1 = e0 + SCHUNK; if (e1 > E) e1 = E;
    for (long j = e0 + tid; j < e1; j += 512) {
        int s = ldidx(ei, j, is64);
        int d = ldidx(ei, (long)E + j, is64);
        int b = d >> BSHIFT;
        int pos = atomicAdd(&cur[b], 1);
        packed[pos] = (s << BSHIFT) | (d & ((1 << BSHIFT) - 1));
    }
}

// ---------------- fine fill: one block per bucket. Self-builds the per-node
// CSR for its 1024 nodes: LDS histogram (LDS atomics) -> 1024-wide block scan ->
// writes rowptr/cnt -> scatters srclist via LDS cursors.
__global__ __launch_bounds__(256) void finefill_kernel(
    const int* __restrict__ bstart,
    const int* __restrict__ packed,
    int* __restrict__ rowptr,
    int* __restrict__ cnt,
    int* __restrict__ srclist)
{
    __shared__ int lcnt[1 << BSHIFT];
    __shared__ int lsum[256];
    int b = blockIdx.x;
    int tid = threadIdx.x;
    int nbase = b << BSHIFT;
    int beg = bstart[b];
    int end = bstart[b + 1];

    for (int i = tid; i < (1 << BSHIFT); i += 256) lcnt[i] = 0;
    __syncthreads();

    // pass 1: in-bucket per-node histogram (LDS atomics)
    for (int j = beg + tid; j < end; j += 256)
        atomicAdd(&lcnt[packed[j] & ((1 << BSHIFT) - 1)], 1);
    __syncthreads();

    // 1024-wide exclusive scan: 4 elems/thread + 256-wide Hillis-Steele
    int i0 = tid * 4;
    int c0 = lcnt[i0], c1 = lcnt[i0 + 1], c2 = lcnt[i0 + 2], c3 = lcnt[i0 + 3];
    lsum[tid] = c0 + c1 + c2 + c3;
    __syncthreads();
    for (int off = 1; off < 256; off <<= 1) {
        int v = lsum[tid];
        if (tid >= off) v += lsum[tid - off];
        __syncthreads();
        lsum[tid] = v;
        __syncthreads();
    }
    int run = beg + ((tid == 0) ? 0 : lsum[tid - 1]);
    int r0 = run, r1 = r0 + c0, r2 = r1 + c1, r3 = r2 + c2;

    int n0 = nbase + i0;
    if (n0     < NT) { rowptr[n0]     = r0; cnt[n0]     = c0; }
    if (n0 + 1 < NT) { rowptr[n0 + 1] = r1; cnt[n0 + 1] = c1; }
    if (n0 + 2 < NT) { rowptr[n0 + 2] = r2; cnt[n0 + 2] = c2; }
    if (n0 + 3 < NT) { rowptr[n0 + 3] = r3; cnt[n0 + 3] = c3; }

    // convert lcnt to running cursors
    lcnt[i0] = r0; lcnt[i0 + 1] = r1; lcnt[i0 + 2] = r2; lcnt[i0 + 3] = r3;
    __syncthreads();

    // pass 2: scatter src ids (stores confined to this bucket's srclist range)
    for (int j = beg + tid; j < end; j += 256) {
        int p = packed[j];
        int dl = p & ((1 << BSHIFT) - 1);
        int pos = atomicAdd(&lcnt[dl], 1);
        srclist[pos] = p >> BSHIFT;
    }
}

// ---------------- fused SAGE layer: xout = act( mean @ Wl.T + b + xin @ Wr.T )
// One block per 64-node tile (4 waves x 16 nodes). Gather phase accumulates the
// neighbor mean in registers (identical to old gather_mean) but deposits bf16
// means into LDS instead of HBM; barrier; MFMA combine consumes lmean. Output
// goes to a DIFFERENT buffer (ping-pong), so own-row A-fragments load straight
// from global (coalesced 2KB/wave) with no in-place hazard and no LDS stage.
// Saves the 35.8MB meanb write + 71.7MB re-read per layer vs split kernels.
template <bool RELU>
__global__ __launch_bounds__(256) void sage_layer(
    const unsigned short* __restrict__ xin,
    const int* __restrict__ rowptr,
    const int* __restrict__ cnt,
    const int* __restrict__ srclist,
    const void* __restrict__ Wl,
    const void* __restrict__ bias,
    const void* __restrict__ Wr,
    unsigned short* __restrict__ xout,
    const int* __restrict__ flags)
{
    __shared__ short8 lWl8[HD * HD / 8];
    __shared__ short8 lWr8[HD * HD / 8];
    __shared__ short8 lmean8[HD * HD / 8];
    __shared__ float lb[HD];
    unsigned short* lWl  = (unsigned short*)lWl8;
    unsigned short* lWr  = (unsigned short*)lWr8;
    unsigned short* lm   = (unsigned short*)lmean8;

    int tid = threadIdx.x;
    int isbf = flags[0];

    // stage weights global->LDS (latency hidden under the gather loop below)
    if (isbf) {
        const short8* wl8 = (const short8*)Wl;
        const short8* wr8 = (const short8*)Wr;
        for (int i = tid; i < HD * HD / 8; i += 256) { lWl8[i] = wl8[i]; lWr8[i] = wr8[i]; }
    } else {
        const floatx4* wlf = (const floatx4*)Wl;
        const floatx4* wrf = (const floatx4*)Wr;
        for (int i = tid; i < HD * HD / 8; i += 256) {
            floatx4 a = wlf[2 * i], b = wlf[2 * i + 1];
            short8 r;
            r[0]=(short)f2bf_raw(a[0]); r[1]=(short)f2bf_raw(a[1]); r[2]=(short)f2bf_raw(a[2]); r[3]=(short)f2bf_raw(a[3]);
            r[4]=(short)f2bf_raw(b[0]); r[5]=(short)f2bf_raw(b[1]); r[6]=(short)f2bf_raw(b[2]); r[7]=(short)f2bf_raw(b[3]);
            lWl8[i] = r;
            a = wrf[2 * i]; b = wrf[2 * i + 1];
            r[0]=(short)f2bf_raw(a[0]); r[1]=(short)f2bf_raw(a[1]); r[2]=(short)f2bf_raw(a[2]); r[3]=(short)f2bf_raw(a[3]);
            r[4]=(short)f2bf_raw(b[0]); r[5]=(short)f2bf_raw(b[1]); r[6]=(short)f2bf_raw(b[2]); r[7]=(short)f2bf_raw(b[3]);
            lWr8[i] = r;
        }
    }
    if (tid < HD) lb[tid] = ldf(bias, tid, isbf);

    int tile = blockIdx.x;                 // 64 nodes per tile; NT = 64*4375 exactly
    long base = (long)tile * HD * HD;

    int w = tid >> 6;
    int lane = tid & 63;
    int mrow = lane & 15;
    int quad = lane >> 4;

    // own-row MFMA A-fragments, loaded early straight from global (xout != xin)
    const short8* xrow = (const short8*)&xin[base + (long)(w * 16 + mrow) * HD];
    short8 ax0 = xrow[quad];        // cols [quad*8, quad*8+8)
    short8 ax1 = xrow[4 + quad];    // cols [32+quad*8, 32+quad*8+8)

    // ---- gather phase: wave w owns nodes tile*64 + w*16 .. +15
    int g = lane >> 2;          // node group 0..15
    int sub = lane & 3;         // 16-elem segment 0..3
    int nl = w * 16 + g;        // node local id 0..63
    int n = tile * 64 + nl;
    int beg = rowptr[n];
    int deg = cnt[n];

    float acc[16];
    #pragma unroll
    for (int k = 0; k < 16; ++k) acc[k] = 0.f;

    for (int j0 = 0; j0 < deg; j0 += 4) {
        int e = j0 + sub;
        int sv = (e < deg) ? srclist[beg + e] : 0;    // 4 coalesced edge-id loads per group
        int cq = deg - j0; if (cq > 4) cq = 4;
        short8 r[4][2];
        #pragma unroll
        for (int q = 0; q < 4; ++q) {                 // 8 independent 16B loads in flight
            int s = __shfl(sv, (g << 2) | q);
            const short8* p = (const short8*)&xin[(long)s * HD + sub * 16];
            r[q][0] = p[0];
            r[q][1] = p[1];
        }
        #pragma unroll
        for (int q = 0; q < 4; ++q) {
            if (q < cq) {
                #pragma unroll
                for (int k = 0; k < 8; ++k) {
                    acc[k]     += bfu2f((unsigned short)r[q][0][k]);
                    acc[k + 8] += bfu2f((unsigned short)r[q][1][k]);
                }
            }
        }
    }

    float rd = 1.0f / fmaxf((float)deg, 1.0f);
    short8 o0, o1;
    #pragma unroll
    for (int k = 0; k < 8; ++k) {
        o0[k] = (short)f2bf_raw(acc[k] * rd);         // same bf16 rounding as old meanb path
        o1[k] = (short)f2bf_raw(acc[k + 8] * rd);
    }
    *(short8*)&lm[nl * HD + sub * 16]     = o0;
    *(short8*)&lm[nl * HD + sub * 16 + 8] = o1;

    __syncthreads();   // lmean + weights ready

    // ---- MFMA combine phase
    short8 am0 = *(const short8*)&lm[(w * 16 + mrow) * HD + quad * 8];
    short8 am1 = *(const short8*)&lm[(w * 16 + mrow) * HD + 32 + quad * 8];

    floatx4 acc4[4];
    #pragma unroll
    for (int ht = 0; ht < 4; ++ht) {
        int h = ht * 16 + mrow;
        short8 bl0 = *(const short8*)&lWl[h * HD + quad * 8];
        short8 bl1 = *(const short8*)&lWl[h * HD + 32 + quad * 8];
        short8 br0 = *(const short8*)&lWr[h * HD + quad * 8];
        short8 br1 = *(const short8*)&lWr[h * HD + 32 + quad * 8];
        floatx4 a = {0.f, 0.f, 0.f, 0.f};
        a = __builtin_amdgcn_mfma_f32_16x16x32_bf16(am0, bl0, a, 0, 0, 0);
        a = __builtin_amdgcn_mfma_f32_16x16x32_bf16(am1, bl1, a, 0, 0, 0);
        a = __builtin_amdgcn_mfma_f32_16x16x32_bf16(ax0, br0, a, 0, 0, 0);
        a = __builtin_amdgcn_mfma_f32_16x16x32_bf16(ax1, br1, a, 0, 0, 0);
        acc4[ht] = a;
    }

    #pragma unroll
    for (int ht = 0; ht < 4; ++ht) {
        int h = ht * 16 + mrow;
        float bv = lb[h];
        #pragma unroll
        for (int r = 0; r < 4; ++r) {
            int node = w * 16 + quad * 4 + r;
            float v = acc4[ht][r] + bv;
            if (RELU) v = fmaxf(v, 0.0f);
            xout[base + node * HD + h] = f2bf_raw(v);
        }
    }
}

// ---------------- final: out[e] = dot(x2[u[e]], x2[NU + m[e]])
// 4 lanes per edge, 16 edges per wave; 16B vector loads; 2-step xor reduce.
__global__ __launch_bounds__(256) void dot_kernel(
    const unsigned short* __restrict__ x2,
    const int* __restrict__ eli,
    void* __restrict__ out,
    int EL,
    const int* __restrict__ flags)
{
    int wid = (blockIdx.x * 256 + threadIdx.x) >> 6;    // global wave id
    long base = (long)wid * 16;                          // first edge of this wave
    if (base >= EL) return;
    int lane = threadIdx.x & 63;
    int isbf = flags[0];
    int is64 = flags[1];

    // lanes 0..15 load u indices, lanes 16..31 load m indices (EL % 16 == 0)
    int idxv = 0;
    if (lane < 16)      idxv = ldidx(eli, base + lane, is64);
    else if (lane < 32) idxv = ldidx(eli, (long)EL + base + (lane - 16), is64);

    int e   = lane >> 2;          // edge slot 0..15
    int seg = lane & 3;           // 16-element segment of the 64-dim row
    int u = __shfl(idxv, e);
    int m = __shfl(idxv, 16 + e);

    const short8* up = (const short8*)(x2 + (long)u * HD + seg * 16);
    const short8* mp = (const short8*)(x2 + (long)(NU + m) * HD + seg * 16);
    short8 a0 = up[0], a1 = up[1];
    short8 b0 = mp[0], b1 = mp[1];

    float p = 0.f;
    #pragma unroll
    for (int j = 0; j < 8; ++j) {
        p += bfu2f((unsigned short)a0[j]) * bfu2f((unsigned short)b0[j]);
        p += bfu2f((unsigned short)a1[j]) * bfu2f((unsigned short)b1[j]);
    }
    p += __shfl_xor(p, 1);
    p += __shfl_xor(p, 2);

    if (seg == 0) {
        long g = base + e;
        if (isbf) ((unsigned short*)out)[g] = f2bf_raw(p);
        else      ((float*)out)[g] = p;
    }
}

extern "C" void kernel_launch(void* const* d_in, const int* in_sizes, int n_in,
                              void* d_out, int out_size, void* d_ws, size_t ws_size,
                              hipStream_t stream)
{
    const void* movie_x   = d_in[0];
    const void* user_emb  = d_in[1];
    const void* movie_emb = d_in[2];
    const void* lin_W     = d_in[3];
    const void* lin_b     = d_in[4];
    const void* W1l       = d_in[5];
    const void* b1        = d_in[6];
    const void* W1r       = d_in[7];
    const void* W2l       = d_in[8];
    const void* b2        = d_in[9];
    const void* W2r       = d_in[10];
    const int* ei  = (const int*)d_in[11];
    const int* eli = (const int*)d_in[12];
    int E  = in_sizes[11] / 2;
    int EL = in_sizes[12] / 2;

    const int NSB = (E + SCHUNK - 1) / SCHUNK;          // hist/scatter blocks (306)

    char* w = (char*)d_ws;
    unsigned short* xb0     = (unsigned short*)w;  w += (size_t)NT * HD * 2;  // 35.84 MB
    unsigned short* xb1     = (unsigned short*)w;  w += (size_t)NT * HD * 2;  // 35.84 MB (ping-pong)
    int*            cnt     = (int*)w;             w += (size_t)NT * 4;
    int*            rowptr  = (int*)w;             w += (size_t)NT * 4;
    int*            srclist = (int*)w;             w += (size_t)E * 4;        // 5 MB
    int*            packed  = (int*)w;             w += (size_t)E * 4;        // 5 MB
    int*            bcnt    = (int*)w;             w += (size_t)(NBUCK + 1) * 4;
    int*            bstart  = (int*)w;             w += (size_t)(NBUCK + 1) * 4;
    int*            blkhist = (int*)w;             w += (size_t)NSB * NBUCK * 4;  // ~335 KB
    int*            flags   = (int*)w;

    const int user_blocks   = (NU * HD / 8) / 256;      // 6250 exactly
    const int movie_blocks  = NM / 16;                  // 5000: 4 waves/block x 4 movies/wave
    const int tile_blocks   = NT / 64;                  // 4375
    const int dot_blocks    = ((EL + 15) / 16 + 3) / 4; // 7813

    probe_kernel<<<1, 64, 0, stream>>>(user_emb, ei, flags);

    prep_user<<<user_blocks, 256, 0, stream>>>(user_emb, xb0, flags);
    prep_movie<<<movie_blocks, 256, 0, stream>>>(movie_x, movie_emb, lin_W, lin_b, xb0, flags);

    // CSR build (once; reused by both layers) -- fully atomic-free global path
    blk_hist<<<NSB, 512, 0, stream>>>(ei, E, blkhist, flags);
    col_scan<<<NBUCK, 256, 0, stream>>>(blkhist, NSB, bcnt);
    bucket_scan<<<1, 256, 0, stream>>>(bcnt, bstart, E);
    scatter_kernel<<<NSB, 512, 0, stream>>>(ei, E, bstart, blkhist, packed, flags);
    finefill_kernel<<<NBUCK, 256, 0, stream>>>(bstart, packed, rowptr, cnt, srclist);

    // fused layers (ping-pong xb0 -> xb1 -> xb0)
    sage_layer<true><<<tile_blocks, 256, 0, stream>>>(xb0, rowptr, cnt, srclist, W1l, b1, W1r, xb1, flags);
    sage_layer<false><<<tile_blocks, 256, 0, stream>>>(xb1, rowptr, cnt, srclist, W2l, b2, W2r, xb0, flags);

    // final edge dot products
    dot_kernel<<<dot_blocks, 256, 0, stream>>>(xb0, eli, d_out, EL, flags);
}

// Round 6
// 305.405 us; speedup vs baseline: 1.3601x; 1.0011x over previous
//
#include <hip/hip_runtime.h>
#include <hip/hip_bf16.h>

#define NU 200000
#define NM 80000
#define NT 280000   // NU + NM
#define HD 64
#define FM 20

#define BSHIFT 10
#define NBUCK ((NT + 1023) >> 10)   // 274 buckets of 1024 nodes
#define SCHUNK 4096                 // edges per hist/scatter block

#define PD 72        // padded LDS row: 72 shorts = 144 B = 9 x 16B slots (odd -> conflict-free)
#define PD8 (PD / 8) // 9 short8 slots per row

typedef __attribute__((ext_vector_type(8))) short short8;
typedef __attribute__((ext_vector_type(4))) float floatx4;

__device__ __forceinline__ float bfu2f(unsigned short u) {
    union { unsigned int u; float f; } c; c.u = ((unsigned int)u) << 16; return c.f;
}

__device__ __forceinline__ unsigned short f2bf_raw(float f) {
    union { float f; unsigned int u; } c; c.f = f;
    unsigned int u = c.u + 0x7FFFu + ((c.u >> 16) & 1u);   // round-nearest-even
    return (unsigned short)(u >> 16);
}

__device__ __forceinline__ float ldf(const void* p, long i, int isbf) {
    return isbf ? bfu2f(((const unsigned short*)p)[i]) : ((const float*)p)[i];
}
__device__ __forceinline__ int ldidx(const int* p, long j, int is64) {
    return is64 ? p[2 * j] : p[j];
}

// ---------------- runtime dtype probe -> flags[0]=isbf16, flags[1]=isint64
__global__ void probe_kernel(const void* user_emb, const int* ei, int* flags) {
    int t = threadIdx.x;
    int bad = 0;
    for (int i = t; i < 128; i += 64) {
        unsigned short h = ((const unsigned short*)user_emb)[i];
        unsigned int e = (h >> 7) & 0xFF;
        if (e >= 135) bad = 1;               // |x| >= 256, or Inf/NaN -> not real bf16
    }
    unsigned long long mf = __ballot(bad != 0);
    int odd_nonzero = 0;
    if (t < 16 && ei[2 * t + 1] != 0) odd_nonzero = 1;
    unsigned long long mi = __ballot(odd_nonzero != 0);
    if (t == 0) {
        flags[0] = (mf == 0) ? 1 : 0;
        flags[1] = (mi == 0) ? 1 : 0;
    }
}

// ---------------- prep A: user rows, vectorized copy/convert (8 elems/thread)
__global__ __launch_bounds__(256) void prep_user(
    const void* __restrict__ user_emb,
    unsigned short* __restrict__ xb,
    const int* __restrict__ flags)
{
    long t = (long)blockIdx.x * 256 + threadIdx.x;        // t < NU*HD/8 = 1.6M exactly
    int isbf = flags[0];
    if (isbf) {
        ((short8*)xb)[t] = ((const short8*)user_emb)[t];
    } else {
        floatx4 a = ((const floatx4*)user_emb)[2 * t];
        floatx4 b = ((const floatx4*)user_emb)[2 * t + 1];
        short8 r;
        r[0] = (short)f2bf_raw(a[0]); r[1] = (short)f2bf_raw(a[1]);
        r[2] = (short)f2bf_raw(a[2]); r[3] = (short)f2bf_raw(a[3]);
        r[4] = (short)f2bf_raw(b[0]); r[5] = (short)f2bf_raw(b[1]);
        r[6] = (short)f2bf_raw(b[2]); r[7] = (short)f2bf_raw(b[3]);
        ((short8*)xb)[t] = r;
    }
}

// ---------------- prep B: movie rows, latency-optimized.
__global__ __launch_bounds__(256) void prep_movie(
    const void* __restrict__ movie_x,
    const void* __restrict__ movie_emb,
    const void* __restrict__ lin_W,
    const void* __restrict__ lin_b,
    unsigned short* __restrict__ xb,
    const int* __restrict__ flags)
{
    int isbf = flags[0];
    int tid = threadIdx.x;
    int lane = tid & 63;
    int wave = blockIdx.x * 4 + (tid >> 6);
    int m0 = __builtin_amdgcn_readfirstlane(wave << 2);   // 4 movies per wave
    if (m0 >= NM) return;

    float wr[FM];
    if (isbf) {
        const unsigned int* p = (const unsigned int*)((const unsigned short*)lin_W + (long)lane * FM);
        #pragma unroll
        for (int i = 0; i < FM / 2; ++i) {
            unsigned int u = p[i];
            wr[2 * i]     = bfu2f((unsigned short)(u & 0xFFFFu));
            wr[2 * i + 1] = bfu2f((unsigned short)(u >> 16));
        }
    } else {
        const floatx4* p = (const floatx4*)((const float*)lin_W + (long)lane * FM);
        #pragma unroll
        for (int i = 0; i < FM / 4; ++i) {
            floatx4 v = p[i];
            wr[4 * i] = v[0]; wr[4 * i + 1] = v[1]; wr[4 * i + 2] = v[2]; wr[4 * i + 3] = v[3];
        }
    }
    float bias = ldf(lin_b, lane, isbf);

    #pragma unroll
    for (int mm = 0; mm < 4; ++mm) {
        int m = m0 + mm;
        float a0 = bias + ldf(movie_emb, (long)m * HD + lane, isbf);
        float a1 = 0.f, a2 = 0.f, a3 = 0.f;
        if (isbf) {
            const unsigned int* mr = (const unsigned int*)((const unsigned short*)movie_x + (long)m * FM);
            #pragma unroll
            for (int kk = 0; kk < FM / 2; ++kk) {
                unsigned int u = mr[kk];
                float x0 = bfu2f((unsigned short)(u & 0xFFFFu));
                float x1 = bfu2f((unsigned short)(u >> 16));
                if (kk & 1) { a2 += x0 * wr[2 * kk]; a3 += x1 * wr[2 * kk + 1]; }
                else        { a0 += x0 * wr[2 * kk]; a1 += x1 * wr[2 * kk + 1]; }
            }
        } else {
            const float* mr = (const float*)movie_x + (long)m * FM;
            #pragma unroll
            for (int k = 0; k < FM; k += 4) {
                a0 += mr[k]     * wr[k];
                a1 += mr[k + 1] * wr[k + 1];
                a2 += mr[k + 2] * wr[k + 2];
                a3 += mr[k + 3] * wr[k + 3];
            }
        }
        xb[(long)(NU + m) * HD + lane] = f2bf_raw((a0 + a1) + (a2 + a3));
    }
}

// ---------------- CSR build v3: atomic-free scatter via 2D histogram scan ----
__global__ __launch_bounds__(512) void blk_hist(
    const int* __restrict__ ei, int E,
    int* __restrict__ blkhist,
    const int* __restrict__ flags)
{
    __shared__ int h[NBUCK];
    int tid = threadIdx.x;
    for (int i = tid; i < NBUCK; i += 512) h[i] = 0;
    __syncthreads();
    int is64 = flags[1];
    long e0 = (long)blockIdx.x * SCHUNK;
    long e1 = e0 + SCHUNK; if (e1 > E) e1 = E;
    for (long j = e0 + tid; j < e1; j += 512) {
        int d = ldidx(ei, (long)E + j, is64);
        atomicAdd(&h[d >> BSHIFT], 1);
    }
    __syncthreads();
    long obase = (long)blockIdx.x * NBUCK;
    for (int i = tid; i < NBUCK; i += 512) blkhist[obase + i] = h[i];
}

__global__ __launch_bounds__(256) void col_scan(
    int* __restrict__ blkhist, int NSB,
    int* __restrict__ bcnt)
{
    __shared__ int larr[2048];
    __shared__ int lsum[256];
    int b = blockIdx.x;
    int t = threadIdx.x;
    for (int i = t; i < NSB; i += 256) larr[i] = blkhist[(long)i * NBUCK + b];
    __syncthreads();
    int C = (NSB + 255) >> 8;
    int beg = t * C;
    int end = beg + C; if (end > NSB) end = NSB; if (beg > NSB) beg = NSB;
    int s = 0;
    for (int i = beg; i < end; ++i) s += larr[i];
    lsum[t] = s;
    __syncthreads();
    for (int off = 1; off < 256; off <<= 1) {
        int v = lsum[t];
        if (t >= off) v += lsum[t - off];
        __syncthreads();
        lsum[t] = v;
        __syncthreads();
    }
    int run = (t == 0) ? 0 : lsum[t - 1];
    for (int i = beg; i < end; ++i) {
        int v = larr[i];
        blkhist[(long)i * NBUCK + b] = run;   // exclusive offset of block i in bucket b
        run += v;
    }
    if (t == 0) bcnt[b] = lsum[255];
}

__global__ __launch_bounds__(256) void bucket_scan(
    const int* __restrict__ bcnt, int* __restrict__ bstart, int E)
{
    __shared__ int s[256];
    int t = threadIdx.x;
    int a0 = (2 * t     < NBUCK) ? bcnt[2 * t]     : 0;
    int a1 = (2 * t + 1 < NBUCK) ? bcnt[2 * t + 1] : 0;
    s[t] = a0 + a1;
    __syncthreads();
    for (int off = 1; off < 256; off <<= 1) {
        int v = s[t];
        if (t >= off) v += s[t - off];
        __syncthreads();
        s[t] = v;
        __syncthreads();
    }
    int run = (t == 0) ? 0 : s[t - 1];
    if (2 * t     < NBUCK) bstart[2 * t]     = run;
    if (2 * t + 1 < NBUCK) bstart[2 * t + 1] = run + a0;
    if (t == 0) bstart[NBUCK] = E;
}

__global__ __launch_bounds__(512) void scatter_kernel(
    const int* __restrict__ ei, int E,
    const int* __restrict__ bstart,
    const int* __restrict__ blkhist,
    int* __restrict__ packed,
    const int* __restrict__ flags)
{
    __shared__ int cur[NBUCK];
    int tid = threadIdx.x;
    long obase = (long)blockIdx.x * NBUCK;
    for (int i = tid; i < NBUCK; i += 512) cur[i] = bstart[i] + blkhist[obase + i];
    __syncthreads();
    int is64 = flags[1];
    long e0 = (long)blockIdx.x * SCHUNK;
    long e1 = e0 + SCHUNK; if (e1 > E) e1 = E;
    for (long j = e0 + tid; j < e1; j += 512) {
        int s = ldidx(ei, j, is64);
        int d = ldidx(ei, (long)E + j, is64);
        int b = d >> BSHIFT;
        int pos = atomicAdd(&cur[b], 1);
        packed[pos] = (s << BSHIFT) | (d & ((1 << BSHIFT) - 1));
    }
}

__global__ __launch_bounds__(256) void finefill_kernel(
    const int* __restrict__ bstart,
    const int* __restrict__ packed,
    int* __restrict__ rowptr,
    int* __restrict__ cnt,
    int* __restrict__ srclist)
{
    __shared__ int lcnt[1 << BSHIFT];
    __shared__ int lsum[256];
    int b = blockIdx.x;
    int tid = threadIdx.x;
    int nbase = b << BSHIFT;
    int beg = bstart[b];
    int end = bstart[b + 1];

    for (int i = tid; i < (1 << BSHIFT); i += 256) lcnt[i] = 0;
    __syncthreads();

    for (int j = beg + tid; j < end; j += 256)
        atomicAdd(&lcnt[packed[j] & ((1 << BSHIFT) - 1)], 1);
    __syncthreads();

    int i0 = tid * 4;
    int c0 = lcnt[i0], c1 = lcnt[i0 + 1], c2 = lcnt[i0 + 2], c3 = lcnt[i0 + 3];
    lsum[tid] = c0 + c1 + c2 + c3;
    __syncthreads();
    for (int off = 1; off < 256; off <<= 1) {
        int v = lsum[tid];
        if (tid >= off) v += lsum[tid - off];
        __syncthreads();
        lsum[tid] = v;
        __syncthreads();
    }
    int run = beg + ((tid == 0) ? 0 : lsum[tid - 1]);
    int r0 = run, r1 = r0 + c0, r2 = r1 + c1, r3 = r2 + c2;

    int n0 = nbase + i0;
    if (n0     < NT) { rowptr[n0]     = r0; cnt[n0]     = c0; }
    if (n0 + 1 < NT) { rowptr[n0 + 1] = r1; cnt[n0 + 1] = c1; }
    if (n0 + 2 < NT) { rowptr[n0 + 2] = r2; cnt[n0 + 2] = c2; }
    if (n0 + 3 < NT) { rowptr[n0 + 3] = r3; cnt[n0 + 3] = c3; }

    lcnt[i0] = r0; lcnt[i0 + 1] = r1; lcnt[i0 + 2] = r2; lcnt[i0 + 3] = r3;
    __syncthreads();

    for (int j = beg + tid; j < end; j += 256) {
        int p = packed[j];
        int dl = p & ((1 << BSHIFT) - 1);
        int pos = atomicAdd(&lcnt[dl], 1);
        srclist[pos] = p >> BSHIFT;
    }
}

// ---------------- fused SAGE layer v2: xout = act( mean @ Wl.T + b + xin @ Wr.T )
// 512 threads = 8 waves per 64-node tile. Gather: 8 lanes/node x 8 nodes/wave,
// 8-edge chunks -> rounds = ceil(maxdeg8/8) (~1.35 avg vs 2.6 before), each row
// load is a contiguous 128B per 8-lane group, 8 independent 16B loads in flight
// per lane. LDS rows padded to 72 shorts (144B = 9 slots, odd) -> bank-conflict-
// free ds_read_b128 in the combine phase. Combine: wave pair (w&3, w>>2) covers
// rows (w&3)*16.. with h-tiles {2*(w>>2), 2*(w>>2)+1}.
template <bool RELU>
__global__ __launch_bounds__(512) void sage_layer(
    const unsigned short* __restrict__ xin,
    const int* __restrict__ rowptr,
    const int* __restrict__ cnt,
    const int* __restrict__ srclist,
    const void* __restrict__ Wl,
    const void* __restrict__ bias,
    const void* __restrict__ Wr,
    unsigned short* __restrict__ xout,
    const int* __restrict__ flags)
{
    __shared__ short8 lWl8[HD * PD8];   // 64 rows x 9 slots
    __shared__ short8 lWr8[HD * PD8];
    __shared__ short8 lm8[HD * PD8];
    __shared__ float lb[HD];

    int tid = threadIdx.x;
    int isbf = flags[0];

    // stage weights global->LDS (padded layout), latency hidden under gather
    if (isbf) {
        const short8* wl8 = (const short8*)Wl;
        const short8* wr8 = (const short8*)Wr;
        int i = tid;                       // i < 512 exactly: row=i>>3, frag=i&7
        int di = (i >> 3) * PD8 + (i & 7);
        lWl8[di] = wl8[i];
        lWr8[di] = wr8[i];
    } else {
        const floatx4* wlf = (const floatx4*)Wl;
        const floatx4* wrf = (const floatx4*)Wr;
        int i = tid;
        int di = (i >> 3) * PD8 + (i & 7);
        floatx4 a = wlf[2 * i], b = wlf[2 * i + 1];
        short8 r;
        r[0]=(short)f2bf_raw(a[0]); r[1]=(short)f2bf_raw(a[1]); r[2]=(short)f2bf_raw(a[2]); r[3]=(short)f2bf_raw(a[3]);
        r[4]=(short)f2bf_raw(b[0]); r[5]=(short)f2bf_raw(b[1]); r[6]=(short)f2bf_raw(b[2]); r[7]=(short)f2bf_raw(b[3]);
        lWl8[di] = r;
        a = wrf[2 * i]; b = wrf[2 * i + 1];
        r[0]=(short)f2bf_raw(a[0]); r[1]=(short)f2bf_raw(a[1]); r[2]=(short)f2bf_raw(a[2]); r[3]=(short)f2bf_raw(a[3]);
        r[4]=(short)f2bf_raw(b[0]); r[5]=(short)f2bf_raw(b[1]); r[6]=(short)f2bf_raw(b[2]); r[7]=(short)f2bf_raw(b[3]);
        lWr8[di] = r;
    }
    if (tid < HD) lb[tid] = ldf(bias, tid, isbf);

    int tile = blockIdx.x;                 // 64 nodes per tile; NT = 64*4375 exactly
    long base = (long)tile * HD * HD;

    int w8 = tid >> 6;          // wave 0..7
    int lane = tid & 63;
    int mrow = lane & 15;
    int quad = lane >> 4;
    int roww = (w8 & 3) * 16 + mrow;   // combine row this lane serves
    int htp  = w8 >> 2;                // h-tile pair selector (0 or 1)

    // own-row MFMA A-fragments straight from global (xout != xin, no hazard)
    const short8* xrow = (const short8*)&xin[base + (long)roww * HD];
    short8 ax0 = xrow[quad];
    short8 ax1 = xrow[quad + 4];

    // ---- gather phase: 8 lanes per node, 8 nodes per wave
    int g = lane >> 3;          // node group 0..7
    int sub = lane & 7;         // 16B fragment 0..7 of the 128B row
    int nl = w8 * 8 + g;        // node local id 0..63
    int n = tile * 64 + nl;
    int beg = rowptr[n];
    int deg = cnt[n];

    float acc[8];
    #pragma unroll
    for (int k = 0; k < 8; ++k) acc[k] = 0.f;

    for (int j0 = 0; j0 < deg; j0 += 8) {
        int e = j0 + sub;
        int sv = (e < deg) ? srclist[beg + e] : 0;    // 8 coalesced ids per group
        int cq = deg - j0; if (cq > 8) cq = 8;
        short8 r[8];
        #pragma unroll
        for (int q = 0; q < 8; ++q) {                 // 8 independent 16B loads in flight
            int s = __shfl(sv, (g << 3) | q);
            r[q] = *(const short8*)&xin[(long)s * HD + sub * 8];
        }
        #pragma unroll
        for (int q = 0; q < 8; ++q) {
            if (q < cq) {
                #pragma unroll
                for (int k = 0; k < 8; ++k)
                    acc[k] += bfu2f((unsigned short)r[q][k]);
            }
        }
    }

    float rd = 1.0f / fmaxf((float)deg, 1.0f);
    short8 o;
    #pragma unroll
    for (int k = 0; k < 8; ++k) o[k] = (short)f2bf_raw(acc[k] * rd);   // same rounding as before
    lm8[nl * PD8 + sub] = o;

    __syncthreads();   // lmean + weights ready

    // ---- MFMA combine phase: this wave covers rows roww (16 of 64) x h-tiles {2*htp, 2*htp+1}
    short8 am0 = lm8[roww * PD8 + quad];
    short8 am1 = lm8[roww * PD8 + 4 + quad];

    floatx4 acc4[2];
    #pragma unroll
    for (int t = 0; t < 2; ++t) {
        int h = (htp * 2 + t) * 16 + mrow;
        short8 bl0 = lWl8[h * PD8 + quad];
        short8 bl1 = lWl8[h * PD8 + 4 + quad];
        short8 br0 = lWr8[h * PD8 + quad];
        short8 br1 = lWr8[h * PD8 + 4 + quad];
        floatx4 a = {0.f, 0.f, 0.f, 0.f};
        a = __builtin_amdgcn_mfma_f32_16x16x32_bf16(am0, bl0, a, 0, 0, 0);
        a = __builtin_amdgcn_mfma_f32_16x16x32_bf16(am1, bl1, a, 0, 0, 0);
        a = __builtin_amdgcn_mfma_f32_16x16x32_bf16(ax0, br0, a, 0, 0, 0);
        a = __builtin_amdgcn_mfma_f32_16x16x32_bf16(ax1, br1, a, 0, 0, 0);
        acc4[t] = a;
    }

    #pragma unroll
    for (int t = 0; t < 2; ++t) {
        int h = (htp * 2 + t) * 16 + mrow;
        float bv = lb[h];
        #pragma unroll
        for (int r = 0; r < 4; ++r) {
            int node = (w8 & 3) * 16 + quad * 4 + r;
            float v = acc4[t][r] + bv;
            if (RELU) v = fmaxf(v, 0.0f);
            xout[base + node * HD + h] = f2bf_raw(v);
        }
    }
}

// ---------------- final: out[e] = dot(x2[u[e]], x2[NU + m[e]])
__global__ __launch_bounds__(256) void dot_kernel(
    const unsigned short* __restrict__ x2,
    const int* __restrict__ eli,
    void* __restrict__ out,
    int EL,
    const int* __restrict__ flags)
{
    int wid = (blockIdx.x * 256 + threadIdx.x) >> 6;    // global wave id
    long base = (long)wid * 16;                          // first edge of this wave
    if (base >= EL) return;
    int lane = threadIdx.x & 63;
    int isbf = flags[0];
    int is64 = flags[1];

    int idxv = 0;
    if (lane < 16)      idxv = ldidx(eli, base + lane, is64);
    else if (lane < 32) idxv = ldidx(eli, (long)EL + base + (lane - 16), is64);

    int e   = lane >> 2;          // edge slot 0..15
    int seg = lane & 3;           // 16-element segment of the 64-dim row
    int u = __shfl(idxv, e);
    int m = __shfl(idxv, 16 + e);

    const short8* up = (const short8*)(x2 + (long)u * HD + seg * 16);
    const short8* mp = (const short8*)(x2 + (long)(NU + m) * HD + seg * 16);
    short8 a0 = up[0], a1 = up[1];
    short8 b0 = mp[0], b1 = mp[1];

    float p = 0.f;
    #pragma unroll
    for (int j = 0; j < 8; ++j) {
        p += bfu2f((unsigned short)a0[j]) * bfu2f((unsigned short)b0[j]);
        p += bfu2f((unsigned short)a1[j]) * bfu2f((unsigned short)b1[j]);
    }
    p += __shfl_xor(p, 1);
    p += __shfl_xor(p, 2);

    if (seg == 0) {
        long g = base + e;
        if (isbf) ((unsigned short*)out)[g] = f2bf_raw(p);
        else      ((float*)out)[g] = p;
    }
}

extern "C" void kernel_launch(void* const* d_in, const int* in_sizes, int n_in,
                              void* d_out, int out_size, void* d_ws, size_t ws_size,
                              hipStream_t stream)
{
    const void* movie_x   = d_in[0];
    const void* user_emb  = d_in[1];
    const void* movie_emb = d_in[2];
    const void* lin_W     = d_in[3];
    const void* lin_b     = d_in[4];
    const void* W1l       = d_in[5];
    const void* b1        = d_in[6];
    const void* W1r       = d_in[7];
    const void* W2l       = d_in[8];
    const void* b2        = d_in[9];
    const void* W2r       = d_in[10];
    const int* ei  = (const int*)d_in[11];
    const int* eli = (const int*)d_in[12];
    int E  = in_sizes[11] / 2;
    int EL = in_sizes[12] / 2;

    const int NSB = (E + SCHUNK - 1) / SCHUNK;          // hist/scatter blocks (306)

    char* w = (char*)d_ws;
    unsigned short* xb0     = (unsigned short*)w;  w += (size_t)NT * HD * 2;  // 35.84 MB
    unsigned short* xb1     = (unsigned short*)w;  w += (size_t)NT * HD * 2;  // 35.84 MB (ping-pong)
    int*            cnt     = (int*)w;             w += (size_t)NT * 4;
    int*            rowptr  = (int*)w;             w += (size_t)NT * 4;
    int*            srclist = (int*)w;             w += (size_t)E * 4;        // 5 MB
    int*            packed  = (int*)w;             w += (size_t)E * 4;        // 5 MB
    int*            bcnt    = (int*)w;             w += (size_t)(NBUCK + 1) * 4;
    int*            bstart  = (int*)w;             w += (size_t)(NBUCK + 1) * 4;
    int*            blkhist = (int*)w;             w += (size_t)NSB * NBUCK * 4;  // ~335 KB
    int*            flags   = (int*)w;

    const int user_blocks   = (NU * HD / 8) / 256;      // 6250 exactly
    const int movie_blocks  = NM / 16;                  // 5000: 4 waves/block x 4 movies/wave
    const int tile_blocks   = NT / 64;                  // 4375 (512-thread blocks)
    const int dot_blocks    = ((EL + 15) / 16 + 3) / 4; // 7813

    probe_kernel<<<1, 64, 0, stream>>>(user_emb, ei, flags);

    prep_user<<<user_blocks, 256, 0, stream>>>(user_emb, xb0, flags);
    prep_movie<<<movie_blocks, 256, 0, stream>>>(movie_x, movie_emb, lin_W, lin_b, xb0, flags);

    // CSR build (once; reused by both layers) -- fully atomic-free global path
    blk_hist<<<NSB, 512, 0, stream>>>(ei, E, blkhist, flags);
    col_scan<<<NBUCK, 256, 0, stream>>>(blkhist, NSB, bcnt);
    bucket_scan<<<1, 256, 0, stream>>>(bcnt, bstart, E);
    scatter_kernel<<<NSB, 512, 0, stream>>>(ei, E, bstart, blkhist, packed, flags);
    finefill_kernel<<<NBUCK, 256, 0, stream>>>(bstart, packed, rowptr, cnt, srclist);

    // fused layers (ping-pong xb0 -> xb1 -> xb0)
    sage_layer<true><<<tile_blocks, 512, 0, stream>>>(xb0, rowptr, cnt, srclist, W1l, b1, W1r, xb1, flags);
    sage_layer<false><<<tile_blocks, 512, 0, stream>>>(xb1, rowptr, cnt, srclist, W2l, b2, W2r, xb0, flags);

    // final edge dot products
    dot_kernel<<<dot_blocks, 256, 0, stream>>>(xb0, eli, d_out, EL, flags);
}